// Round 8
// baseline (1076.890 us; speedup 1.0000x reference)
//
#include <hip/hip_runtime.h>
#include <math.h>

#define HID 128
#define DEPTH 4
#define PSPLIT 16
#define SMAXB 40

typedef _Float16 half8 __attribute__((ext_vector_type(8)));
typedef float f4 __attribute__((ext_vector_type(4)));

// ---------------------------------------------------------------- node embed
__global__ void k_node_embed(const float* __restrict__ x, const float* __restrict__ nw,
                             const float* __restrict__ nb, float* __restrict__ h, int N) {
    int idx = blockIdx.x * blockDim.x + threadIdx.x;
    if (idx >= N * HID) return;
    int n = idx >> 7, c = idx & 127;
    float acc = nb[c];
#pragma unroll
    for (int d = 0; d < 4; ++d) acc += x[n * 4 + d] * nw[d * HID + c];
    h[idx] = acc;
}

// ---------------------------------------------------------------- W split+transpose (once per launch)
__global__ void k_wsplit(const float* __restrict__ fkw, _Float16* __restrict__ whi,
                         _Float16* __restrict__ wlo) {
    __shared__ float sh[64][65];
    int bid = blockIdx.x;           // 4 layers * 16 kblk * 2 nblk = 128 blocks
    int l = bid >> 5; int r = bid & 31; int kb = r >> 1; int nbk = r & 1;
    const float* W = fkw + (size_t)l * 131072;
    _Float16* Hl = whi + (size_t)l * 131072;
    _Float16* Ll = wlo + (size_t)l * 131072;
    int k0 = kb * 64, n0 = nbk * 64;
    for (int i = threadIdx.x; i < 4096; i += 256) {
        int kk = i >> 6, nn = i & 63;
        sh[kk][nn] = W[(k0 + kk) * HID + n0 + nn];
    }
    __syncthreads();
    for (int i = threadIdx.x; i < 4096; i += 256) {
        int nn = i >> 6, kk = i & 63;
        float w = sh[kk][nn];
        _Float16 hi = (_Float16)w;
        _Float16 lo = (_Float16)((w - (float)hi) * 2048.f);
        Hl[(n0 + nn) * 1024 + k0 + kk] = hi;
        Ll[(n0 + nn) * 1024 + k0 + kk] = lo;
    }
}

// ---------------------------------------------------------------- CSR build
__global__ void k_hist(const int* __restrict__ dst, int* __restrict__ deg, int E) {
    int e = blockIdx.x * 256 + threadIdx.x;
    if (e < E) atomicAdd(&deg[dst[e]], 1);
}

__global__ void k_scan_a(const int* __restrict__ deg, int* __restrict__ bsum, int N) {
    __shared__ int sh[256];
    int i = blockIdx.x * 256 + threadIdx.x;
    sh[threadIdx.x] = (i < N) ? deg[i] : 0;
    __syncthreads();
    for (int off = 128; off > 0; off >>= 1) {
        if (threadIdx.x < (unsigned)off) sh[threadIdx.x] += sh[threadIdx.x + off];
        __syncthreads();
    }
    if (threadIdx.x == 0) bsum[blockIdx.x] = sh[0];
}

__global__ void k_scan_b(int* __restrict__ bsum, int nb) {
    __shared__ int sh[256];
    int v = (threadIdx.x < (unsigned)nb) ? bsum[threadIdx.x] : 0;
    sh[threadIdx.x] = v;
    __syncthreads();
    for (int off = 1; off < 256; off <<= 1) {
        int add = (threadIdx.x >= (unsigned)off) ? sh[threadIdx.x - off] : 0;
        __syncthreads();
        sh[threadIdx.x] += add;
        __syncthreads();
    }
    if (threadIdx.x < (unsigned)nb) bsum[threadIdx.x] = sh[threadIdx.x] - v;
}

__global__ void k_scan_c(const int* __restrict__ deg, const int* __restrict__ bsum,
                         int* __restrict__ offs, int* __restrict__ cursor, int N) {
    __shared__ int sh[256];
    int i = blockIdx.x * 256 + threadIdx.x;
    int v = (i < N) ? deg[i] : 0;
    sh[threadIdx.x] = v;
    __syncthreads();
    for (int off = 1; off < 256; off <<= 1) {
        int add = (threadIdx.x >= (unsigned)off) ? sh[threadIdx.x - off] : 0;
        __syncthreads();
        sh[threadIdx.x] += add;
        __syncthreads();
    }
    int ex = bsum[blockIdx.x] + sh[threadIdx.x] - v;
    if (i < N) { offs[i] = ex; cursor[i] = ex; }
    if (i == N - 1) offs[N] = ex + v;
}

__global__ void k_scatter(const int* __restrict__ src, const int* __restrict__ dst,
                          int* cursor, int* __restrict__ eord,
                          int* __restrict__ srco, int E) {
    int e = blockIdx.x * 256 + threadIdx.x;
    if (e < E) {
        int d = dst[e];
        int p = atomicAdd(&cursor[d], 1);
        eord[p] = e;
        srco[p] = src[e];
    }
}

__global__ void k_eaord(const int* __restrict__ eord, const float* __restrict__ ea,
                        float4* __restrict__ ea3o, int E) {
    int idx = blockIdx.x * 256 + threadIdx.x;
    if (idx >= E) return;
    int e = eord[idx];
    float4 q;
    q.x = ea[e * 3 + 0]; q.y = ea[e * 3 + 1]; q.z = ea[e * 3 + 2]; q.w = 0.f;
    ea3o[idx] = q;
}

__global__ void k_bstart(const int* __restrict__ batch, int* __restrict__ boffs, int N, int B) {
    int n = blockIdx.x * 256 + threadIdx.x;
    if (n >= N) return;
    int b1 = batch[n];
    if (n == 0) for (int b = 0; b <= b1; ++b) boffs[b] = 0;
    int b2 = (n + 1 < N) ? batch[n + 1] : B;
    for (int b = b1 + 1; b <= b2; ++b) boffs[b] = n + 1;
}

// ---------------------------------------------------------------- attention dots
__global__ void k_att(const float* __restrict__ h, const float* __restrict__ attw,
                      const float* __restrict__ attb, float* __restrict__ a1,
                      float* __restrict__ a2, int N) {
    __shared__ float r1[4], r2[4];
    int half = threadIdx.x >> 7;
    int c = threadIdx.x & 127;
    int n = blockIdx.x * 2 + half;
    float hv = (n < N) ? h[n * HID + c] : 0.f;
    float p1 = hv * attw[c];
    float p2 = hv * attw[128 + c];
    for (int off = 32; off > 0; off >>= 1) {
        p1 += __shfl_down(p1, off);
        p2 += __shfl_down(p2, off);
    }
    int wid = threadIdx.x >> 6;
    if ((threadIdx.x & 63) == 0) { r1[wid] = p1; r2[wid] = p2; }
    __syncthreads();
    if ((threadIdx.x & 127) == 0 && n < N) {
        a1[n] = r1[half * 2] + r1[half * 2 + 1] + attb[0];
        a2[n] = r2[half * 2] + r2[half * 2 + 1];
    }
}

// ---------------------------------------------------------------- per-node linear (A1,A2)
__global__ __launch_bounds__(256) void k_node_lin(const float* __restrict__ h,
                           const float* __restrict__ linw, const float* __restrict__ linb,
                           float* __restrict__ A1, float* __restrict__ A2, int N) {
    __shared__ float hT[HID][12];
    int nb = blockIdx.x * 8;
    int tid = threadIdx.x;
    for (int i = tid; i < 8 * HID; i += 256) {
        int n = i >> 7, c = i & 127;
        int gn = nb + n;
        hT[c][n] = (gn < N) ? h[gn * HID + c] : 0.f;
    }
    __syncthreads();
    int c = tid & 127, r = tid >> 7;
    const float* Wd = linw;
    const float* Ws = linw + 128 * HID;
    float acc1[4] = {0, 0, 0, 0}, acc2[4] = {0, 0, 0, 0};
#pragma unroll 4
    for (int k = 0; k < HID; ++k) {
        float wd = Wd[k * HID + c];
        float ws = Ws[k * HID + c];
        float4 hv = *(const float4*)&hT[k][r * 4];
        acc1[0] += hv.x * wd; acc2[0] += hv.x * ws;
        acc1[1] += hv.y * wd; acc2[1] += hv.y * ws;
        acc1[2] += hv.z * wd; acc2[2] += hv.z * ws;
        acc1[3] += hv.w * wd; acc2[3] += hv.w * ws;
    }
#pragma unroll
    for (int j = 0; j < 4; ++j) {
        int gn = nb + r * 4 + j;
        if (gn < N) {
            A1[gn * HID + c] = acc1[j] + linb[c];
            A2[gn * HID + c] = acc2[j];
        }
    }
}

// ---------------------------------------------------------------- edge conv (CSR, 8 slots, float4, alpha fused)
__global__ __launch_bounds__(256) void k_edge(const float* __restrict__ A1,
        const float* __restrict__ A2, const float* __restrict__ a1,
        const float* __restrict__ a2, const int* __restrict__ srco,
        const float4* __restrict__ ea3o, const int* __restrict__ offs,
        const float* __restrict__ linw3, const float* __restrict__ attw3,
        float* __restrict__ hconv, int N) {
    __shared__ float w3s[3 * HID];
    __shared__ float aw3s[3];
    __shared__ float part[8][HID];
    int n = blockIdx.x;
    int tid = threadIdx.x;        // 256 threads = 8 edge slots x 32 lanes x 4 channels
    int lane32 = tid & 31, slot = tid >> 5;
    int c4 = lane32 * 4;
    for (int i = tid; i < 3 * HID; i += 256) w3s[i] = linw3[i];
    if (tid < 3) aw3s[tid] = attw3[tid];
    __syncthreads();
    float4 w0v = *(const float4*)&w3s[c4];
    float4 w1v = *(const float4*)&w3s[HID + c4];
    float4 w2v = *(const float4*)&w3s[2 * HID + c4];
    float aw0 = aw3s[0], aw1 = aw3s[1], aw2 = aw3s[2];
    float a1n = a1[n];
    float4 A1v = *(const float4*)&A1[(size_t)n * HID + c4];
    float4 acc; acc.x = acc.y = acc.z = acc.w = 0.f;
    int s0 = offs[n], s1 = offs[n + 1];
    for (int idx = s0 + slot; idx < s1; idx += 8) {
        int s = srco[idx];
        float4 q = ea3o[idx];
        float logit = a1n + a2[s] + q.x * aw0 + q.y * aw1 + q.z * aw2;
        float al = 1.f / (1.f + __expf(-logit));
        float4 a2v = *(const float4*)&A2[(size_t)s * HID + c4];
        float4 pre;
        pre.x = A1v.x + a2v.x + q.x * w0v.x + q.y * w1v.x + q.z * w2v.x;
        pre.y = A1v.y + a2v.y + q.x * w0v.y + q.y * w1v.y + q.z * w2v.y;
        pre.z = A1v.z + a2v.z + q.x * w0v.z + q.y * w1v.z + q.z * w2v.z;
        pre.w = A1v.w + a2v.w + q.x * w0v.w + q.y * w1v.w + q.z * w2v.w;
        acc.x += al * pre.x; acc.y += al * pre.y;
        acc.z += al * pre.z; acc.w += al * pre.w;
    }
    *(float4*)&part[slot][c4] = acc;
    __syncthreads();
    for (int st = 4; st >= 1; st >>= 1) {
        if (slot < st) {
            float4 p = *(const float4*)&part[slot][c4];
            float4 r = *(const float4*)&part[slot + st][c4];
            p.x += r.x; p.y += r.y; p.z += r.z; p.w += r.w;
            *(float4*)&part[slot][c4] = p;
        }
        __syncthreads();
    }
    if (slot == 0) *(float4*)&hconv[(size_t)n * HID + c4] = *(const float4*)&part[0][c4];
}

// ---------------------------------------------------------------- Fourier-Kolmogorov GEMM
// Fused trig + split-f16 MFMA. Wave = 16 exclusive rows x 64 cols x 512 K.
// Block = 256 thr = 2 row-groups x 2 col-halves. NO LDS, NO barriers: each lane
// preloads its own row's 32 needed h values into registers; K-loop is a pure
// register-trig + coalesced-W-load + MFMA stream.
__global__ __launch_bounds__(256, 4) void k_fk(const float* __restrict__ h,
        const _Float16* __restrict__ whi, const _Float16* __restrict__ wlo,
        float* __restrict__ p0, float* __restrict__ p1, int N) {
    int bx = blockIdx.x;
    int nb = (bx >> 1) * 32;
    int ks = bx & 1;
    int kbase = ks * 512;
    int tid = threadIdx.x, lane = tid & 63, wv = tid >> 6;
    int wm = wv >> 1, wn = wv & 1;
    int quad = lane >> 4, l16 = lane & 15;
    int row = nb + wm * 16 + l16;
    int rclamp = (row < N) ? row : (N - 1);
    // preload: hr[t] = h[row][quad*8 + t*32 .. +8)
    float4 hr[4][2];
#pragma unroll
    for (int t = 0; t < 4; ++t) {
        const float* hp = h + (size_t)rclamp * HID + quad * 8 + t * 32;
        hr[t][0] = *(const float4*)hp;
        hr[t][1] = *(const float4*)(hp + 4);
    }
    int col0 = wn * 64;
    f4 acc0[4], accL[4];
#pragma unroll
    for (int ni = 0; ni < 4; ++ni) { acc0[ni] = (f4)(0.f); accL[ni] = (f4)(0.f); }
    const _Float16* bph[4];
    const _Float16* bpl[4];
#pragma unroll
    for (int ni = 0; ni < 4; ++ni) {
        size_t off = (size_t)(col0 + ni * 16 + l16) * 1024 + kbase + quad * 8;
        bph[ni] = whi + off;
        bpl[ni] = wlo + off;
    }
#pragma unroll 4
    for (int s = 0; s < 16; ++s) {
        int t = s & 3;
        int fr = (kbase >> 7) + (s >> 2);             // frequency index 0..7
        float freqf = 6.2831853f * (float)(fr + 1);
        float hv[8] = {hr[t][0].x, hr[t][0].y, hr[t][0].z, hr[t][0].w,
                       hr[t][1].x, hr[t][1].y, hr[t][1].z, hr[t][1].w};
        half8 ah, al;
#pragma unroll
        for (int j = 0; j < 8; ++j) {
            float ang = freqf * hv[j] + 0.78539816f;
            float a = 1.41421356f * __sinf(ang);      // sin + cos
            _Float16 hi = (_Float16)a;
            ah[j] = hi;
            al[j] = (_Float16)((a - (float)hi) * 2048.f);
        }
        int ko = s * 32;
        half8 bh[4], bl[4];
#pragma unroll
        for (int ni = 0; ni < 4; ++ni) {
            bh[ni] = *(const half8*)(bph[ni] + ko);
            bl[ni] = *(const half8*)(bpl[ni] + ko);
        }
#pragma unroll
        for (int ni = 0; ni < 4; ++ni) {
            acc0[ni] = __builtin_amdgcn_mfma_f32_16x16x32_f16(ah, bh[ni], acc0[ni], 0, 0, 0);
            accL[ni] = __builtin_amdgcn_mfma_f32_16x16x32_f16(ah, bl[ni], accL[ni], 0, 0, 0);
            accL[ni] = __builtin_amdgcn_mfma_f32_16x16x32_f16(al, bh[ni], accL[ni], 0, 0, 0);
        }
    }
    float* p = ks ? p1 : p0;
    const float inv = 1.0f / 2048.0f;
#pragma unroll
    for (int ni = 0; ni < 4; ++ni)
#pragma unroll
        for (int r = 0; r < 4; ++r) {
            int gn = nb + wm * 16 + quad * 4 + r;
            if (gn < N)
                p[(size_t)gn * HID + col0 + ni * 16 + l16] = acc0[ni][r] + accL[ni][r] * inv;
        }
}

// ---------------------------------------------------------------- batchnorm stats
__global__ void k_bn_stats(float* __restrict__ hconv,
                           const float* __restrict__ p0, const float* __restrict__ p1,
                           const float* __restrict__ fkb,
                           double* __restrict__ stats, int N) {
    int c = threadIdx.x & 127, half = threadIdx.x >> 7;
    float bias = fkb[c];
    float s = 0.f, s2 = 0.f;
    for (int n = blockIdx.x * 2 + half; n < N; n += gridDim.x * 2) {
        int idx = n * HID + c;
        float v = hconv[idx] + p0[idx] + p1[idx] + bias;
        hconv[idx] = v;
        s += v; s2 += v * v;
    }
    __shared__ float sh[256], sh2[256];
    sh[threadIdx.x] = s; sh2[threadIdx.x] = s2;
    __syncthreads();
    if (half == 0) {
        s = sh[c] + sh[128 + c];
        s2 = sh2[c] + sh2[128 + c];
        atomicAdd(&stats[c], (double)s);
        atomicAdd(&stats[128 + c], (double)s2);
    }
}

// bn_final folded in; optionally computes pool scores (last layer)
__global__ void k_bn_apply(const float* __restrict__ hsum, const double* __restrict__ stats,
                           const float* __restrict__ g, const float* __restrict__ b,
                           const float* __restrict__ pw, const float* __restrict__ pb,
                           float* __restrict__ h, float* __restrict__ s,
                           int do_score, int N) {
    __shared__ float red[4];
    int idx = blockIdx.x * 256 + threadIdx.x;
    int valid = idx < N * HID;
    int c = idx & 127;
    double invN = 1.0 / (double)N;
    float mu = (float)(stats[c] * invN);
    float var = (float)(stats[128 + c] * invN) - mu * mu;
    float inv = 1.f / sqrtf(var + 1e-5f);
    float sc = g[c] * inv;
    float sh = b[c] - mu * sc;
    float o = 0.f;
    if (valid) {
        o = fmaxf(hsum[idx] * sc + sh, 0.f);
        h[idx] = o;
    }
    if (do_score) {
        float p = valid ? o * pw[c] : 0.f;
        for (int off = 32; off > 0; off >>= 1) p += __shfl_down(p, off);
        int wid = threadIdx.x >> 6;
        if ((threadIdx.x & 63) == 0) red[wid] = p;
        __syncthreads();
        int row = idx >> 7;
        int half = threadIdx.x >> 7;
        if ((threadIdx.x & 127) == 0 && row < N)
            s[row] = red[half * 2] + red[half * 2 + 1] + pb[0];
    }
}

// ---------------------------------------------------------------- softmax partials
__global__ void k_smax1(const float* __restrict__ s, float* __restrict__ mzp, int N) {
    __shared__ float red[256];
    float m = -INFINITY;
    for (int n = blockIdx.x * 256 + threadIdx.x; n < N; n += SMAXB * 256)
        m = fmaxf(m, s[n]);
    red[threadIdx.x] = m;
    __syncthreads();
    for (int off = 128; off > 0; off >>= 1) {
        if (threadIdx.x < (unsigned)off)
            red[threadIdx.x] = fmaxf(red[threadIdx.x], red[threadIdx.x + off]);
        __syncthreads();
    }
    m = red[0];
    __syncthreads();
    float z = 0.f;
    for (int n = blockIdx.x * 256 + threadIdx.x; n < N; n += SMAXB * 256)
        z += __expf(s[n] - m);
    red[threadIdx.x] = z;
    __syncthreads();
    for (int off = 128; off > 0; off >>= 1) {
        if (threadIdx.x < (unsigned)off) red[threadIdx.x] += red[threadIdx.x + off];
        __syncthreads();
    }
    if (threadIdx.x == 0) { mzp[blockIdx.x * 2] = m; mzp[blockIdx.x * 2 + 1] = red[0]; }
}

__device__ __forceinline__ void combine_mz(const float* mzp, float& m, float& Z) {
    m = -INFINITY;
#pragma unroll 8
    for (int i = 0; i < SMAXB; ++i) m = fmaxf(m, mzp[i * 2]);
    Z = 0.f;
#pragma unroll 8
    for (int i = 0; i < SMAXB; ++i) Z += mzp[i * 2 + 1] * __expf(mzp[i * 2] - m);
}

// ---------------------------------------------------------------- attention pool (split)
__global__ void k_pool_part(const float* __restrict__ h, const float* __restrict__ s,
                            const float* __restrict__ mzp, const int* __restrict__ boffs,
                            float* __restrict__ part) {
    int b = blockIdx.x >> 4, split = blockIdx.x & (PSPLIT - 1);
    int c = threadIdx.x & 127, half = threadIdx.x >> 7;
    float m, Z;
    combine_mz(mzp, m, Z);
    (void)Z;
    int n0 = boffs[b], n1 = boffs[b + 1];
    float acc = 0.f;
    for (int n = n0 + split * 2 + half; n < n1; n += PSPLIT * 2)
        acc += __expf(s[n] - m) * h[n * HID + c];
    __shared__ float prt[2][HID];
    prt[half][c] = acc;
    __syncthreads();
    if (half == 0) part[(size_t)(b * PSPLIT + split) * HID + c] = prt[0][c] + prt[1][c];
}

__global__ void k_pool_sum(const float* __restrict__ part, const float* __restrict__ mzp,
                           float* __restrict__ pooled) {
    int b = blockIdx.x, c = threadIdx.x;
    float m, Z;
    combine_mz(mzp, m, Z);
    float acc = 0.f;
#pragma unroll
    for (int i = 0; i < PSPLIT; ++i) acc += part[(size_t)(b * PSPLIT + i) * HID + c];
    pooled[b * HID + c] = acc / Z;
}

// ---------------------------------------------------------------- heads (grid = B*4)
__global__ __launch_bounds__(256) void k_head(const float* __restrict__ pooled,
                       const float* __restrict__ sg_table,
                       const int* __restrict__ space_group,
                       const float* __restrict__ hw1, const float* __restrict__ hb1,
                       const float* __restrict__ ew2, const float* __restrict__ eb2,
                       const float* __restrict__ sw2, const float* __restrict__ sb2,
                       const float* __restrict__ cw2, const float* __restrict__ cb2,
                       const float* __restrict__ mw2, const float* __restrict__ mb2,
                       float* __restrict__ out, int B) {
    __shared__ float comb[256];
    __shared__ float zred[2][128];
    __shared__ float zsh[128];
    int b = blockIdx.x >> 2, i = blockIdx.x & 3;
    int t = threadIdx.x;
    comb[t] = (t < 128) ? pooled[b * HID + t] : sg_table[space_group[b] * HID + (t - 128)];
    __syncthreads();
    int half = t >> 7, tt = t & 127;
    const float* W = hw1 + ((size_t)i * 256 + half * 128) * HID;
    const float* cb = &comb[half * 128];
    float z = 0.f;
#pragma unroll 8
    for (int k = 0; k < 128; ++k) z += cb[k] * W[k * HID + tt];
    zred[half][tt] = z;
    __syncthreads();
    if (t < 128) zsh[t] = fmaxf(zred[0][t] + zred[1][t] + hb1[i * HID + t], 0.f);
    __syncthreads();
    const int od[4] = {1, 3, 7, 3};
    const int base[4] = {0, 64, 256, 704};
    const float* w2 = (i == 0) ? ew2 : (i == 1) ? sw2 : (i == 2) ? cw2 : mw2;
    const float* b2 = (i == 0) ? eb2 : (i == 1) ? sb2 : (i == 2) ? cb2 : mb2;
    int odi = od[i];
    if (t < odi) {
        float o = b2[t];
        for (int c = 0; c < HID; ++c) o += zsh[c] * w2[c * odi + t];
        out[base[i] + b * odi + t] = o;
    }
}

// ---------------------------------------------------------------- launch
extern "C" void kernel_launch(void* const* d_in, const int* in_sizes, int n_in,
                              void* d_out, int out_size, void* d_ws, size_t ws_size,
                              hipStream_t stream) {
    const float* x          = (const float*)d_in[0];
    const int*   edge_index = (const int*)d_in[1];
    const float* edge_attr  = (const float*)d_in[2];
    const int*   batch      = (const int*)d_in[3];
    const int*   space_group= (const int*)d_in[4];
    const float* node_w     = (const float*)d_in[5];
    const float* node_b     = (const float*)d_in[6];
    const float* sg_table   = (const float*)d_in[7];
    const float* lin_w      = (const float*)d_in[8];
    const float* lin_b      = (const float*)d_in[9];
    const float* att_w      = (const float*)d_in[10];
    const float* att_b      = (const float*)d_in[11];
    const float* fk_w       = (const float*)d_in[12];
    const float* fk_b       = (const float*)d_in[13];
    const float* bn_g       = (const float*)d_in[14];
    const float* bn_b       = (const float*)d_in[15];
    const float* pool_w     = (const float*)d_in[16];
    const float* pool_b     = (const float*)d_in[17];
    const float* head_w1    = (const float*)d_in[18];
    const float* head_b1    = (const float*)d_in[19];
    const float* ew2 = (const float*)d_in[20]; const float* eb2 = (const float*)d_in[21];
    const float* sw2 = (const float*)d_in[22]; const float* sb2 = (const float*)d_in[23];
    const float* cw2 = (const float*)d_in[24]; const float* cb2 = (const float*)d_in[25];
    const float* mw2 = (const float*)d_in[26]; const float* mb2 = (const float*)d_in[27];
    float* out = (float*)d_out;

    const int N = in_sizes[3];
    const int E = in_sizes[1] / 2;
    const int B = in_sizes[4];
    const int* src = edge_index;
    const int* dst = edge_index + E;

    char* w = (char*)d_ws;
    auto alloc = [&](size_t bytes) { char* p = w; w += (bytes + 255) & ~(size_t)255; return p; };
    float*  h      = (float*)alloc((size_t)N * HID * 4);
    float*  A1     = (float*)alloc((size_t)N * HID * 4);  // reused as FK partial 0
    float*  A2     = (float*)alloc((size_t)N * HID * 4);  // reused as FK partial 1
    float*  hconv  = (float*)alloc((size_t)N * HID * 4);  // becomes pre-BN sum in place
    float*  a1     = (float*)alloc((size_t)N * 4);
    float*  a2     = (float*)alloc((size_t)N * 4);
    float*  sbuf   = (float*)alloc((size_t)N * 4);
    int*    deg    = (int*)alloc((size_t)N * 4);
    int*    cursor = (int*)alloc((size_t)N * 4);
    int*    offs   = (int*)alloc((size_t)(N + 1) * 4);
    int*    eord   = (int*)alloc((size_t)E * 4);
    int*    srco   = (int*)alloc((size_t)E * 4);
    float4* ea3o   = (float4*)alloc((size_t)E * 16);
    _Float16* whi  = (_Float16*)alloc((size_t)DEPTH * 1024 * HID * 2);
    _Float16* wlo  = (_Float16*)alloc((size_t)DEPTH * 1024 * HID * 2);
    int*    bsum   = (int*)alloc(256 * 4);
    int*    boffs  = (int*)alloc((size_t)(B + 1) * 4);
    double* stats  = (double*)alloc(256 * 8);
    float*  mzp    = (float*)alloc(SMAXB * 2 * 4);
    float*  part   = (float*)alloc((size_t)B * PSPLIT * HID * 4);
    float*  pooled = (float*)alloc((size_t)B * HID * 4);

    const int nchunk = (N + 255) / 256;
    const int echunk = (E + 255) / 256;

    // one-time per launch: W split + CSR build
    k_wsplit<<<128, 256, 0, stream>>>(fk_w, whi, wlo);
    hipMemsetAsync(deg, 0, (size_t)N * 4, stream);
    k_hist<<<echunk, 256, 0, stream>>>(dst, deg, E);
    k_scan_a<<<nchunk, 256, 0, stream>>>(deg, bsum, N);
    k_scan_b<<<1, 256, 0, stream>>>(bsum, nchunk);
    k_scan_c<<<nchunk, 256, 0, stream>>>(deg, bsum, offs, cursor, N);
    k_scatter<<<echunk, 256, 0, stream>>>(src, dst, cursor, eord, srco, E);
    k_eaord<<<echunk, 256, 0, stream>>>(eord, edge_attr, ea3o, E);
    k_bstart<<<nchunk, 256, 0, stream>>>(batch, boffs, N, B);

    k_node_embed<<<(N * HID + 255) / 256, 256, 0, stream>>>(x, node_w, node_b, h, N);

    for (int l = 0; l < DEPTH; ++l) {
        const float* linw_l = lin_w + (size_t)l * 259 * HID;
        k_node_lin<<<(N + 7) / 8, 256, 0, stream>>>(h, linw_l, lin_b + l * HID, A1, A2, N);
        k_att<<<(N + 1) / 2, 256, 0, stream>>>(h, att_w + (size_t)l * 259, att_b + l, a1, a2, N);
        k_edge<<<N, 256, 0, stream>>>(A1, A2, a1, a2, srco, ea3o, offs,
                                      linw_l + 256 * HID, att_w + (size_t)l * 259 + 256,
                                      hconv, N);
        k_fk<<<((N + 31) / 32) * 2, 256, 0, stream>>>(
            h, whi + (size_t)l * 131072, wlo + (size_t)l * 131072, A1, A2, N);
        hipMemsetAsync(stats, 0, 256 * 8, stream);
        k_bn_stats<<<200, 256, 0, stream>>>(hconv, A1, A2, fk_b + l * HID, stats, N);
        k_bn_apply<<<(N * HID + 255) / 256, 256, 0, stream>>>(
            hconv, stats, bn_g + l * HID, bn_b + l * HID, pool_w, pool_b,
            h, sbuf, (l == DEPTH - 1) ? 1 : 0, N);
    }

    k_smax1<<<SMAXB, 256, 0, stream>>>(sbuf, mzp, N);
    k_pool_part<<<B * PSPLIT, 256, 0, stream>>>(h, sbuf, mzp, boffs, part);
    k_pool_sum<<<B, 128, 0, stream>>>(part, mzp, pooled);
    k_head<<<B * 4, 256, 0, stream>>>(pooled, sg_table, space_group, head_w1, head_b1,
                                      ew2, eb2, sw2, sb2, cw2, cb2, mw2, mb2, out, B);
}

// Round 9
// 846.703 us; speedup vs baseline: 1.2719x; 1.2719x over previous
//
#include <hip/hip_runtime.h>
#include <math.h>

#define HID 128
#define DEPTH 4
#define PSPLIT 16
#define SMAXB 40

typedef _Float16 half8 __attribute__((ext_vector_type(8)));
typedef float f4 __attribute__((ext_vector_type(4)));

// ---------------------------------------------------------------- node embed
__global__ void k_node_embed(const float* __restrict__ x, const float* __restrict__ nw,
                             const float* __restrict__ nb, float* __restrict__ h, int N) {
    int idx = blockIdx.x * blockDim.x + threadIdx.x;
    if (idx >= N * HID) return;
    int n = idx >> 7, c = idx & 127;
    float acc = nb[c];
#pragma unroll
    for (int d = 0; d < 4; ++d) acc += x[n * 4 + d] * nw[d * HID + c];
    h[idx] = acc;
}

// ---------------------------------------------------------------- W split+transpose (once per launch)
__global__ void k_wsplit(const float* __restrict__ fkw, _Float16* __restrict__ whi,
                         _Float16* __restrict__ wlo) {
    __shared__ float sh[64][65];
    int bid = blockIdx.x;           // 4 layers * 16 kblk * 2 nblk = 128 blocks
    int l = bid >> 5; int r = bid & 31; int kb = r >> 1; int nbk = r & 1;
    const float* W = fkw + (size_t)l * 131072;
    _Float16* Hl = whi + (size_t)l * 131072;
    _Float16* Ll = wlo + (size_t)l * 131072;
    int k0 = kb * 64, n0 = nbk * 64;
    for (int i = threadIdx.x; i < 4096; i += 256) {
        int kk = i >> 6, nn = i & 63;
        sh[kk][nn] = W[(k0 + kk) * HID + n0 + nn];
    }
    __syncthreads();
    for (int i = threadIdx.x; i < 4096; i += 256) {
        int nn = i >> 6, kk = i & 63;
        float w = sh[kk][nn];
        _Float16 hi = (_Float16)w;
        _Float16 lo = (_Float16)((w - (float)hi) * 2048.f);
        Hl[(n0 + nn) * 1024 + k0 + kk] = hi;
        Ll[(n0 + nn) * 1024 + k0 + kk] = lo;
    }
}

// ---------------------------------------------------------------- CSR build
__global__ void k_hist(const int* __restrict__ dst, int* __restrict__ deg, int E) {
    int e = blockIdx.x * 256 + threadIdx.x;
    if (e < E) atomicAdd(&deg[dst[e]], 1);
}

__global__ void k_scan_a(const int* __restrict__ deg, int* __restrict__ bsum, int N) {
    __shared__ int sh[256];
    int i = blockIdx.x * 256 + threadIdx.x;
    sh[threadIdx.x] = (i < N) ? deg[i] : 0;
    __syncthreads();
    for (int off = 128; off > 0; off >>= 1) {
        if (threadIdx.x < (unsigned)off) sh[threadIdx.x] += sh[threadIdx.x + off];
        __syncthreads();
    }
    if (threadIdx.x == 0) bsum[blockIdx.x] = sh[0];
}

__global__ void k_scan_b(int* __restrict__ bsum, int nb) {
    __shared__ int sh[256];
    int v = (threadIdx.x < (unsigned)nb) ? bsum[threadIdx.x] : 0;
    sh[threadIdx.x] = v;
    __syncthreads();
    for (int off = 1; off < 256; off <<= 1) {
        int add = (threadIdx.x >= (unsigned)off) ? sh[threadIdx.x - off] : 0;
        __syncthreads();
        sh[threadIdx.x] += add;
        __syncthreads();
    }
    if (threadIdx.x < (unsigned)nb) bsum[threadIdx.x] = sh[threadIdx.x] - v;
}

__global__ void k_scan_c(const int* __restrict__ deg, const int* __restrict__ bsum,
                         int* __restrict__ offs, int* __restrict__ cursor, int N) {
    __shared__ int sh[256];
    int i = blockIdx.x * 256 + threadIdx.x;
    int v = (i < N) ? deg[i] : 0;
    sh[threadIdx.x] = v;
    __syncthreads();
    for (int off = 1; off < 256; off <<= 1) {
        int add = (threadIdx.x >= (unsigned)off) ? sh[threadIdx.x - off] : 0;
        __syncthreads();
        sh[threadIdx.x] += add;
        __syncthreads();
    }
    int ex = bsum[blockIdx.x] + sh[threadIdx.x] - v;
    if (i < N) { offs[i] = ex; cursor[i] = ex; }
    if (i == N - 1) offs[N] = ex + v;
}

__global__ void k_scatter(const int* __restrict__ src, const int* __restrict__ dst,
                          int* cursor, int* __restrict__ eord,
                          int* __restrict__ srco, int E) {
    int e = blockIdx.x * 256 + threadIdx.x;
    if (e < E) {
        int d = dst[e];
        int p = atomicAdd(&cursor[d], 1);
        eord[p] = e;
        srco[p] = src[e];
    }
}

__global__ void k_eaord(const int* __restrict__ eord, const float* __restrict__ ea,
                        float4* __restrict__ ea3o, int E) {
    int idx = blockIdx.x * 256 + threadIdx.x;
    if (idx >= E) return;
    int e = eord[idx];
    float4 q;
    q.x = ea[e * 3 + 0]; q.y = ea[e * 3 + 1]; q.z = ea[e * 3 + 2]; q.w = 0.f;
    ea3o[idx] = q;
}

__global__ void k_bstart(const int* __restrict__ batch, int* __restrict__ boffs, int N, int B) {
    int n = blockIdx.x * 256 + threadIdx.x;
    if (n >= N) return;
    int b1 = batch[n];
    if (n == 0) for (int b = 0; b <= b1; ++b) boffs[b] = 0;
    int b2 = (n + 1 < N) ? batch[n + 1] : B;
    for (int b = b1 + 1; b <= b2; ++b) boffs[b] = n + 1;
}

// ---------------------------------------------------------------- attention dots
__global__ void k_att(const float* __restrict__ h, const float* __restrict__ attw,
                      const float* __restrict__ attb, float* __restrict__ a1,
                      float* __restrict__ a2, int N) {
    __shared__ float r1[4], r2[4];
    int half = threadIdx.x >> 7;
    int c = threadIdx.x & 127;
    int n = blockIdx.x * 2 + half;
    float hv = (n < N) ? h[n * HID + c] : 0.f;
    float p1 = hv * attw[c];
    float p2 = hv * attw[128 + c];
    for (int off = 32; off > 0; off >>= 1) {
        p1 += __shfl_down(p1, off);
        p2 += __shfl_down(p2, off);
    }
    int wid = threadIdx.x >> 6;
    if ((threadIdx.x & 63) == 0) { r1[wid] = p1; r2[wid] = p2; }
    __syncthreads();
    if ((threadIdx.x & 127) == 0 && n < N) {
        a1[n] = r1[half * 2] + r1[half * 2 + 1] + attb[0];
        a2[n] = r2[half * 2] + r2[half * 2 + 1];
    }
}

// ---------------------------------------------------------------- per-node linear (A1,A2)
__global__ __launch_bounds__(256) void k_node_lin(const float* __restrict__ h,
                           const float* __restrict__ linw, const float* __restrict__ linb,
                           float* __restrict__ A1, float* __restrict__ A2, int N) {
    __shared__ float hT[HID][12];
    int nb = blockIdx.x * 8;
    int tid = threadIdx.x;
    for (int i = tid; i < 8 * HID; i += 256) {
        int n = i >> 7, c = i & 127;
        int gn = nb + n;
        hT[c][n] = (gn < N) ? h[gn * HID + c] : 0.f;
    }
    __syncthreads();
    int c = tid & 127, r = tid >> 7;
    const float* Wd = linw;
    const float* Ws = linw + 128 * HID;
    float acc1[4] = {0, 0, 0, 0}, acc2[4] = {0, 0, 0, 0};
#pragma unroll 4
    for (int k = 0; k < HID; ++k) {
        float wd = Wd[k * HID + c];
        float ws = Ws[k * HID + c];
        float4 hv = *(const float4*)&hT[k][r * 4];
        acc1[0] += hv.x * wd; acc2[0] += hv.x * ws;
        acc1[1] += hv.y * wd; acc2[1] += hv.y * ws;
        acc1[2] += hv.z * wd; acc2[2] += hv.z * ws;
        acc1[3] += hv.w * wd; acc2[3] += hv.w * ws;
    }
#pragma unroll
    for (int j = 0; j < 4; ++j) {
        int gn = nb + r * 4 + j;
        if (gn < N) {
            A1[gn * HID + c] = acc1[j] + linb[c];
            A2[gn * HID + c] = acc2[j];
        }
    }
}

// ---------------------------------------------------------------- edge conv (CSR, 8 slots, float4, alpha fused)
__global__ __launch_bounds__(256) void k_edge(const float* __restrict__ A1,
        const float* __restrict__ A2, const float* __restrict__ a1,
        const float* __restrict__ a2, const int* __restrict__ srco,
        const float4* __restrict__ ea3o, const int* __restrict__ offs,
        const float* __restrict__ linw3, const float* __restrict__ attw3,
        float* __restrict__ hconv, int N) {
    __shared__ float w3s[3 * HID];
    __shared__ float aw3s[3];
    __shared__ float part[8][HID];
    int n = blockIdx.x;
    int tid = threadIdx.x;        // 256 threads = 8 edge slots x 32 lanes x 4 channels
    int lane32 = tid & 31, slot = tid >> 5;
    int c4 = lane32 * 4;
    for (int i = tid; i < 3 * HID; i += 256) w3s[i] = linw3[i];
    if (tid < 3) aw3s[tid] = attw3[tid];
    __syncthreads();
    float4 w0v = *(const float4*)&w3s[c4];
    float4 w1v = *(const float4*)&w3s[HID + c4];
    float4 w2v = *(const float4*)&w3s[2 * HID + c4];
    float aw0 = aw3s[0], aw1 = aw3s[1], aw2 = aw3s[2];
    float a1n = a1[n];
    float4 A1v = *(const float4*)&A1[(size_t)n * HID + c4];
    float4 acc; acc.x = acc.y = acc.z = acc.w = 0.f;
    int s0 = offs[n], s1 = offs[n + 1];
    for (int idx = s0 + slot; idx < s1; idx += 8) {
        int s = srco[idx];
        float4 q = ea3o[idx];
        float logit = a1n + a2[s] + q.x * aw0 + q.y * aw1 + q.z * aw2;
        float al = 1.f / (1.f + __expf(-logit));
        float4 a2v = *(const float4*)&A2[(size_t)s * HID + c4];
        float4 pre;
        pre.x = A1v.x + a2v.x + q.x * w0v.x + q.y * w1v.x + q.z * w2v.x;
        pre.y = A1v.y + a2v.y + q.x * w0v.y + q.y * w1v.y + q.z * w2v.y;
        pre.z = A1v.z + a2v.z + q.x * w0v.z + q.y * w1v.z + q.z * w2v.z;
        pre.w = A1v.w + a2v.w + q.x * w0v.w + q.y * w1v.w + q.z * w2v.w;
        acc.x += al * pre.x; acc.y += al * pre.y;
        acc.z += al * pre.z; acc.w += al * pre.w;
    }
    *(float4*)&part[slot][c4] = acc;
    __syncthreads();
    for (int st = 4; st >= 1; st >>= 1) {
        if (slot < st) {
            float4 p = *(const float4*)&part[slot][c4];
            float4 r = *(const float4*)&part[slot + st][c4];
            p.x += r.x; p.y += r.y; p.z += r.z; p.w += r.w;
            *(float4*)&part[slot][c4] = p;
        }
        __syncthreads();
    }
    if (slot == 0) *(float4*)&hconv[(size_t)n * HID + c4] = *(const float4*)&part[0][c4];
}

// ---------------------------------------------------------------- Fourier-Kolmogorov GEMM (split-f16 MFMA)
// R6 structure (LDS h-tile, register trig, no K-loop barriers) with K-split 4:
// grid = tiles*4 -> ~9.8 blocks/CU -> occupancy cap 32 waves/CU (was 19.5).
#define FK_LDSH 132
__global__ __launch_bounds__(256) void k_fk(const float* __restrict__ h,
        const _Float16* __restrict__ whi, const _Float16* __restrict__ wlo,
        float* __restrict__ p0, float* __restrict__ p1,
        float* __restrict__ p2, float* __restrict__ p3, int N) {
    __shared__ float hsh[32 * FK_LDSH];
    int tid = threadIdx.x;
    int bx = blockIdx.x;
    int nb = (bx >> 2) * 32;
    int ks = bx & 3;
    int kbase = ks * 256;
    for (int i = tid; i < 32 * 32; i += 256) {
        int nn = i >> 5, c4 = (i & 31) * 4;
        int gn = nb + nn;
        float4 v = (gn < N) ? *(const float4*)&h[gn * HID + c4] : make_float4(0.f, 0.f, 0.f, 0.f);
        *(float4*)&hsh[nn * FK_LDSH + c4] = v;
    }
    __syncthreads();
    int lane = tid & 63, wv = tid >> 6;
    int quad = lane >> 4, l16 = lane & 15;
    int n0w = wv * 32;
    f4 acc0[2][2], accL[2][2];
#pragma unroll
    for (int mi = 0; mi < 2; ++mi)
#pragma unroll
        for (int ni = 0; ni < 2; ++ni) { acc0[mi][ni] = (f4)(0.f); accL[mi][ni] = (f4)(0.f); }
    const _Float16* bhp0 = whi + (size_t)(n0w + l16) * 1024 + kbase + quad * 8;
    const _Float16* bhp1 = whi + (size_t)(n0w + 16 + l16) * 1024 + kbase + quad * 8;
    const _Float16* blp0 = wlo + (size_t)(n0w + l16) * 1024 + kbase + quad * 8;
    const _Float16* blp1 = wlo + (size_t)(n0w + 16 + l16) * 1024 + kbase + quad * 8;
#pragma unroll 2
    for (int step = 0; step < 8; ++step) {
        int kg0 = kbase + step * 32 + quad * 8;
        int fr = kg0 >> 7;
        int ii = kg0 & 127;
        float freqf = 6.2831853f * (float)(fr + 1);
        half8 ah[2], al[2];
#pragma unroll
        for (int mi = 0; mi < 2; ++mi) {
            const float* hp = &hsh[(mi * 16 + l16) * FK_LDSH + ii];
            float4 h0 = *(const float4*)hp;
            float4 h1 = *(const float4*)(hp + 4);
            float hv[8] = {h0.x, h0.y, h0.z, h0.w, h1.x, h1.y, h1.z, h1.w};
#pragma unroll
            for (int j = 0; j < 8; ++j) {
                float ang = freqf * hv[j] + 0.78539816f;
                float a = 1.41421356f * __sinf(ang);
                _Float16 hi = (_Float16)a;
                ah[mi][j] = hi;
                al[mi][j] = (_Float16)((a - (float)hi) * 2048.f);
            }
        }
        int ko = step * 32;
        half8 bh0 = *(const half8*)(bhp0 + ko);
        half8 bh1 = *(const half8*)(bhp1 + ko);
        half8 bl0 = *(const half8*)(blp0 + ko);
        half8 bl1 = *(const half8*)(blp1 + ko);
        acc0[0][0] = __builtin_amdgcn_mfma_f32_16x16x32_f16(ah[0], bh0, acc0[0][0], 0, 0, 0);
        acc0[0][1] = __builtin_amdgcn_mfma_f32_16x16x32_f16(ah[0], bh1, acc0[0][1], 0, 0, 0);
        acc0[1][0] = __builtin_amdgcn_mfma_f32_16x16x32_f16(ah[1], bh0, acc0[1][0], 0, 0, 0);
        acc0[1][1] = __builtin_amdgcn_mfma_f32_16x16x32_f16(ah[1], bh1, acc0[1][1], 0, 0, 0);
        accL[0][0] = __builtin_amdgcn_mfma_f32_16x16x32_f16(ah[0], bl0, accL[0][0], 0, 0, 0);
        accL[0][1] = __builtin_amdgcn_mfma_f32_16x16x32_f16(ah[0], bl1, accL[0][1], 0, 0, 0);
        accL[1][0] = __builtin_amdgcn_mfma_f32_16x16x32_f16(ah[1], bl0, accL[1][0], 0, 0, 0);
        accL[1][1] = __builtin_amdgcn_mfma_f32_16x16x32_f16(ah[1], bl1, accL[1][1], 0, 0, 0);
        accL[0][0] = __builtin_amdgcn_mfma_f32_16x16x32_f16(al[0], bh0, accL[0][0], 0, 0, 0);
        accL[0][1] = __builtin_amdgcn_mfma_f32_16x16x32_f16(al[0], bh1, accL[0][1], 0, 0, 0);
        accL[1][0] = __builtin_amdgcn_mfma_f32_16x16x32_f16(al[1], bh0, accL[1][0], 0, 0, 0);
        accL[1][1] = __builtin_amdgcn_mfma_f32_16x16x32_f16(al[1], bh1, accL[1][1], 0, 0, 0);
    }
    float* p = (ks == 0) ? p0 : (ks == 1) ? p1 : (ks == 2) ? p2 : p3;
    const float inv = 1.0f / 2048.0f;
#pragma unroll
    for (int mi = 0; mi < 2; ++mi)
#pragma unroll
        for (int ni = 0; ni < 2; ++ni)
#pragma unroll
            for (int r = 0; r < 4; ++r) {
                int gn = nb + mi * 16 + quad * 4 + r;
                if (gn < N)
                    p[gn * HID + n0w + ni * 16 + l16] = acc0[mi][ni][r] + accL[mi][ni][r] * inv;
            }
}

// ---------------------------------------------------------------- batchnorm stats (5 streams)
__global__ void k_bn_stats(float* __restrict__ hconv,
                           const float* __restrict__ p0, const float* __restrict__ p1,
                           const float* __restrict__ p2, const float* __restrict__ p3,
                           const float* __restrict__ fkb,
                           double* __restrict__ stats, int N) {
    int c = threadIdx.x & 127, half = threadIdx.x >> 7;
    float bias = fkb[c];
    float s = 0.f, s2 = 0.f;
    for (int n = blockIdx.x * 2 + half; n < N; n += gridDim.x * 2) {
        int idx = n * HID + c;
        float v = hconv[idx] + p0[idx] + p1[idx] + p2[idx] + p3[idx] + bias;
        hconv[idx] = v;
        s += v; s2 += v * v;
    }
    __shared__ float sh[256], sh2[256];
    sh[threadIdx.x] = s; sh2[threadIdx.x] = s2;
    __syncthreads();
    if (half == 0) {
        s = sh[c] + sh[128 + c];
        s2 = sh2[c] + sh2[128 + c];
        atomicAdd(&stats[c], (double)s);
        atomicAdd(&stats[128 + c], (double)s2);
    }
}

// bn_final folded in; optionally computes pool scores (last layer)
__global__ void k_bn_apply(const float* __restrict__ hsum, const double* __restrict__ stats,
                           const float* __restrict__ g, const float* __restrict__ b,
                           const float* __restrict__ pw, const float* __restrict__ pb,
                           float* __restrict__ h, float* __restrict__ s,
                           int do_score, int N) {
    __shared__ float red[4];
    int idx = blockIdx.x * 256 + threadIdx.x;
    int valid = idx < N * HID;
    int c = idx & 127;
    double invN = 1.0 / (double)N;
    float mu = (float)(stats[c] * invN);
    float var = (float)(stats[128 + c] * invN) - mu * mu;
    float inv = 1.f / sqrtf(var + 1e-5f);
    float sc = g[c] * inv;
    float sh = b[c] - mu * sc;
    float o = 0.f;
    if (valid) {
        o = fmaxf(hsum[idx] * sc + sh, 0.f);
        h[idx] = o;
    }
    if (do_score) {
        float p = valid ? o * pw[c] : 0.f;
        for (int off = 32; off > 0; off >>= 1) p += __shfl_down(p, off);
        int wid = threadIdx.x >> 6;
        if ((threadIdx.x & 63) == 0) red[wid] = p;
        __syncthreads();
        int row = idx >> 7;
        int half = threadIdx.x >> 7;
        if ((threadIdx.x & 127) == 0 && row < N)
            s[row] = red[half * 2] + red[half * 2 + 1] + pb[0];
    }
}

// ---------------------------------------------------------------- softmax partials
__global__ void k_smax1(const float* __restrict__ s, float* __restrict__ mzp, int N) {
    __shared__ float red[256];
    float m = -INFINITY;
    for (int n = blockIdx.x * 256 + threadIdx.x; n < N; n += SMAXB * 256)
        m = fmaxf(m, s[n]);
    red[threadIdx.x] = m;
    __syncthreads();
    for (int off = 128; off > 0; off >>= 1) {
        if (threadIdx.x < (unsigned)off)
            red[threadIdx.x] = fmaxf(red[threadIdx.x], red[threadIdx.x + off]);
        __syncthreads();
    }
    m = red[0];
    __syncthreads();
    float z = 0.f;
    for (int n = blockIdx.x * 256 + threadIdx.x; n < N; n += SMAXB * 256)
        z += __expf(s[n] - m);
    red[threadIdx.x] = z;
    __syncthreads();
    for (int off = 128; off > 0; off >>= 1) {
        if (threadIdx.x < (unsigned)off) red[threadIdx.x] += red[threadIdx.x + off];
        __syncthreads();
    }
    if (threadIdx.x == 0) { mzp[blockIdx.x * 2] = m; mzp[blockIdx.x * 2 + 1] = red[0]; }
}

__device__ __forceinline__ void combine_mz(const float* mzp, float& m, float& Z) {
    m = -INFINITY;
#pragma unroll 8
    for (int i = 0; i < SMAXB; ++i) m = fmaxf(m, mzp[i * 2]);
    Z = 0.f;
#pragma unroll 8
    for (int i = 0; i < SMAXB; ++i) Z += mzp[i * 2 + 1] * __expf(mzp[i * 2] - m);
}

// ---------------------------------------------------------------- attention pool (split)
__global__ void k_pool_part(const float* __restrict__ h, const float* __restrict__ s,
                            const float* __restrict__ mzp, const int* __restrict__ boffs,
                            float* __restrict__ part) {
    int b = blockIdx.x >> 4, split = blockIdx.x & (PSPLIT - 1);
    int c = threadIdx.x & 127, half = threadIdx.x >> 7;
    float m, Z;
    combine_mz(mzp, m, Z);
    (void)Z;
    int n0 = boffs[b], n1 = boffs[b + 1];
    float acc = 0.f;
    for (int n = n0 + split * 2 + half; n < n1; n += PSPLIT * 2)
        acc += __expf(s[n] - m) * h[n * HID + c];
    __shared__ float prt[2][HID];
    prt[half][c] = acc;
    __syncthreads();
    if (half == 0) part[(size_t)(b * PSPLIT + split) * HID + c] = prt[0][c] + prt[1][c];
}

__global__ void k_pool_sum(const float* __restrict__ part, const float* __restrict__ mzp,
                           float* __restrict__ pooled) {
    int b = blockIdx.x, c = threadIdx.x;
    float m, Z;
    combine_mz(mzp, m, Z);
    float acc = 0.f;
#pragma unroll
    for (int i = 0; i < PSPLIT; ++i) acc += part[(size_t)(b * PSPLIT + i) * HID + c];
    pooled[b * HID + c] = acc / Z;
}

// ---------------------------------------------------------------- heads (grid = B*4)
__global__ __launch_bounds__(256) void k_head(const float* __restrict__ pooled,
                       const float* __restrict__ sg_table,
                       const int* __restrict__ space_group,
                       const float* __restrict__ hw1, const float* __restrict__ hb1,
                       const float* __restrict__ ew2, const float* __restrict__ eb2,
                       const float* __restrict__ sw2, const float* __restrict__ sb2,
                       const float* __restrict__ cw2, const float* __restrict__ cb2,
                       const float* __restrict__ mw2, const float* __restrict__ mb2,
                       float* __restrict__ out, int B) {
    __shared__ float comb[256];
    __shared__ float zred[2][128];
    __shared__ float zsh[128];
    int b = blockIdx.x >> 2, i = blockIdx.x & 3;
    int t = threadIdx.x;
    comb[t] = (t < 128) ? pooled[b * HID + t] : sg_table[space_group[b] * HID + (t - 128)];
    __syncthreads();
    int half = t >> 7, tt = t & 127;
    const float* W = hw1 + ((size_t)i * 256 + half * 128) * HID;
    const float* cb = &comb[half * 128];
    float z = 0.f;
#pragma unroll 8
    for (int k = 0; k < 128; ++k) z += cb[k] * W[k * HID + tt];
    zred[half][tt] = z;
    __syncthreads();
    if (t < 128) zsh[t] = fmaxf(zred[0][t] + zred[1][t] + hb1[i * HID + t], 0.f);
    __syncthreads();
    const int od[4] = {1, 3, 7, 3};
    const int base[4] = {0, 64, 256, 704};
    const float* w2 = (i == 0) ? ew2 : (i == 1) ? sw2 : (i == 2) ? cw2 : mw2;
    const float* b2 = (i == 0) ? eb2 : (i == 1) ? sb2 : (i == 2) ? cb2 : mb2;
    int odi = od[i];
    if (t < odi) {
        float o = b2[t];
        for (int c = 0; c < HID; ++c) o += zsh[c] * w2[c * odi + t];
        out[base[i] + b * odi + t] = o;
    }
}

// ---------------------------------------------------------------- launch
extern "C" void kernel_launch(void* const* d_in, const int* in_sizes, int n_in,
                              void* d_out, int out_size, void* d_ws, size_t ws_size,
                              hipStream_t stream) {
    const float* x          = (const float*)d_in[0];
    const int*   edge_index = (const int*)d_in[1];
    const float* edge_attr  = (const float*)d_in[2];
    const int*   batch      = (const int*)d_in[3];
    const int*   space_group= (const int*)d_in[4];
    const float* node_w     = (const float*)d_in[5];
    const float* node_b     = (const float*)d_in[6];
    const float* sg_table   = (const float*)d_in[7];
    const float* lin_w      = (const float*)d_in[8];
    const float* lin_b      = (const float*)d_in[9];
    const float* att_w      = (const float*)d_in[10];
    const float* att_b      = (const float*)d_in[11];
    const float* fk_w       = (const float*)d_in[12];
    const float* fk_b       = (const float*)d_in[13];
    const float* bn_g       = (const float*)d_in[14];
    const float* bn_b       = (const float*)d_in[15];
    const float* pool_w     = (const float*)d_in[16];
    const float* pool_b     = (const float*)d_in[17];
    const float* head_w1    = (const float*)d_in[18];
    const float* head_b1    = (const float*)d_in[19];
    const float* ew2 = (const float*)d_in[20]; const float* eb2 = (const float*)d_in[21];
    const float* sw2 = (const float*)d_in[22]; const float* sb2 = (const float*)d_in[23];
    const float* cw2 = (const float*)d_in[24]; const float* cb2 = (const float*)d_in[25];
    const float* mw2 = (const float*)d_in[26]; const float* mb2 = (const float*)d_in[27];
    float* out = (float*)d_out;

    const int N = in_sizes[3];
    const int E = in_sizes[1] / 2;
    const int B = in_sizes[4];
    const int* src = edge_index;
    const int* dst = edge_index + E;

    char* w = (char*)d_ws;
    auto alloc = [&](size_t bytes) { char* p = w; w += (bytes + 255) & ~(size_t)255; return p; };
    float*  h      = (float*)alloc((size_t)N * HID * 4);
    float*  A1     = (float*)alloc((size_t)N * HID * 4);  // reused as FK partial 0
    float*  A2     = (float*)alloc((size_t)N * HID * 4);  // reused as FK partial 1
    float*  p2     = (float*)alloc((size_t)N * HID * 4);  // FK partial 2
    float*  p3     = (float*)alloc((size_t)N * HID * 4);  // FK partial 3
    float*  hconv  = (float*)alloc((size_t)N * HID * 4);  // becomes pre-BN sum in place
    float*  a1     = (float*)alloc((size_t)N * 4);
    float*  a2     = (float*)alloc((size_t)N * 4);
    float*  sbuf   = (float*)alloc((size_t)N * 4);
    int*    deg    = (int*)alloc((size_t)N * 4);
    int*    cursor = (int*)alloc((size_t)N * 4);
    int*    offs   = (int*)alloc((size_t)(N + 1) * 4);
    int*    eord   = (int*)alloc((size_t)E * 4);
    int*    srco   = (int*)alloc((size_t)E * 4);
    float4* ea3o   = (float4*)alloc((size_t)E * 16);
    _Float16* whi  = (_Float16*)alloc((size_t)DEPTH * 1024 * HID * 2);
    _Float16* wlo  = (_Float16*)alloc((size_t)DEPTH * 1024 * HID * 2);
    int*    bsum   = (int*)alloc(256 * 4);
    int*    boffs  = (int*)alloc((size_t)(B + 1) * 4);
    double* stats  = (double*)alloc(256 * 8);
    float*  mzp    = (float*)alloc(SMAXB * 2 * 4);
    float*  part   = (float*)alloc((size_t)B * PSPLIT * HID * 4);
    float*  pooled = (float*)alloc((size_t)B * HID * 4);

    const int nchunk = (N + 255) / 256;
    const int echunk = (E + 255) / 256;

    // one-time per launch: W split + CSR build
    k_wsplit<<<128, 256, 0, stream>>>(fk_w, whi, wlo);
    hipMemsetAsync(deg, 0, (size_t)N * 4, stream);
    k_hist<<<echunk, 256, 0, stream>>>(dst, deg, E);
    k_scan_a<<<nchunk, 256, 0, stream>>>(deg, bsum, N);
    k_scan_b<<<1, 256, 0, stream>>>(bsum, nchunk);
    k_scan_c<<<nchunk, 256, 0, stream>>>(deg, bsum, offs, cursor, N);
    k_scatter<<<echunk, 256, 0, stream>>>(src, dst, cursor, eord, srco, E);
    k_eaord<<<echunk, 256, 0, stream>>>(eord, edge_attr, ea3o, E);
    k_bstart<<<nchunk, 256, 0, stream>>>(batch, boffs, N, B);

    k_node_embed<<<(N * HID + 255) / 256, 256, 0, stream>>>(x, node_w, node_b, h, N);

    for (int l = 0; l < DEPTH; ++l) {
        const float* linw_l = lin_w + (size_t)l * 259 * HID;
        k_node_lin<<<(N + 7) / 8, 256, 0, stream>>>(h, linw_l, lin_b + l * HID, A1, A2, N);
        k_att<<<(N + 1) / 2, 256, 0, stream>>>(h, att_w + (size_t)l * 259, att_b + l, a1, a2, N);
        k_edge<<<N, 256, 0, stream>>>(A1, A2, a1, a2, srco, ea3o, offs,
                                      linw_l + 256 * HID, att_w + (size_t)l * 259 + 256,
                                      hconv, N);
        k_fk<<<((N + 31) / 32) * 4, 256, 0, stream>>>(
            h, whi + (size_t)l * 131072, wlo + (size_t)l * 131072, A1, A2, p2, p3, N);
        hipMemsetAsync(stats, 0, 256 * 8, stream);
        k_bn_stats<<<200, 256, 0, stream>>>(hconv, A1, A2, p2, p3, fk_b + l * HID, stats, N);
        k_bn_apply<<<(N * HID + 255) / 256, 256, 0, stream>>>(
            hconv, stats, bn_g + l * HID, bn_b + l * HID, pool_w, pool_b,
            h, sbuf, (l == DEPTH - 1) ? 1 : 0, N);
    }

    k_smax1<<<SMAXB, 256, 0, stream>>>(sbuf, mzp, N);
    k_pool_part<<<B * PSPLIT, 256, 0, stream>>>(h, sbuf, mzp, boffs, part);
    k_pool_sum<<<B, 128, 0, stream>>>(part, mzp, pooled);
    k_head<<<B * 4, 256, 0, stream>>>(pooled, sg_table, space_group, head_w1, head_b1,
                                      ew2, eb2, sw2, sb2, cw2, cb2, mw2, mb2, out, B);
}

// Round 10
// 819.270 us; speedup vs baseline: 1.3145x; 1.0335x over previous
//
#include <hip/hip_runtime.h>
#include <math.h>

#define HID 128
#define DEPTH 4
#define PSPLIT 16
#define SMAXB 40

typedef _Float16 half8 __attribute__((ext_vector_type(8)));
typedef float f4 __attribute__((ext_vector_type(4)));

// ---------------------------------------------------------------- node embed
__global__ void k_node_embed(const float* __restrict__ x, const float* __restrict__ nw,
                             const float* __restrict__ nb, float* __restrict__ h, int N) {
    int idx = blockIdx.x * blockDim.x + threadIdx.x;
    if (idx >= N * HID) return;
    int n = idx >> 7, c = idx & 127;
    float acc = nb[c];
#pragma unroll
    for (int d = 0; d < 4; ++d) acc += x[n * 4 + d] * nw[d * HID + c];
    h[idx] = acc;
}

// ---------------------------------------------------------------- W split+transpose (once per launch)
__global__ void k_wsplit(const float* __restrict__ fkw, _Float16* __restrict__ whi,
                         _Float16* __restrict__ wlo) {
    __shared__ float sh[64][65];
    int bid = blockIdx.x;           // 4 layers * 16 kblk * 2 nblk = 128 blocks
    int l = bid >> 5; int r = bid & 31; int kb = r >> 1; int nbk = r & 1;
    const float* W = fkw + (size_t)l * 131072;
    _Float16* Hl = whi + (size_t)l * 131072;
    _Float16* Ll = wlo + (size_t)l * 131072;
    int k0 = kb * 64, n0 = nbk * 64;
    for (int i = threadIdx.x; i < 4096; i += 256) {
        int kk = i >> 6, nn = i & 63;
        sh[kk][nn] = W[(k0 + kk) * HID + n0 + nn];
    }
    __syncthreads();
    for (int i = threadIdx.x; i < 4096; i += 256) {
        int nn = i >> 6, kk = i & 63;
        float w = sh[kk][nn];
        _Float16 hi = (_Float16)w;
        _Float16 lo = (_Float16)((w - (float)hi) * 2048.f);
        Hl[(n0 + nn) * 1024 + k0 + kk] = hi;
        Ll[(n0 + nn) * 1024 + k0 + kk] = lo;
    }
}

// ---------------------------------------------------------------- CSR build
__global__ void k_hist(const int* __restrict__ dst, int* __restrict__ deg, int E) {
    int e = blockIdx.x * 256 + threadIdx.x;
    if (e < E) atomicAdd(&deg[dst[e]], 1);
}

__global__ void k_scan_a(const int* __restrict__ deg, int* __restrict__ bsum, int N) {
    __shared__ int sh[256];
    int i = blockIdx.x * 256 + threadIdx.x;
    sh[threadIdx.x] = (i < N) ? deg[i] : 0;
    __syncthreads();
    for (int off = 128; off > 0; off >>= 1) {
        if (threadIdx.x < (unsigned)off) sh[threadIdx.x] += sh[threadIdx.x + off];
        __syncthreads();
    }
    if (threadIdx.x == 0) bsum[blockIdx.x] = sh[0];
}

__global__ void k_scan_b(int* __restrict__ bsum, int nb) {
    __shared__ int sh[256];
    int v = (threadIdx.x < (unsigned)nb) ? bsum[threadIdx.x] : 0;
    sh[threadIdx.x] = v;
    __syncthreads();
    for (int off = 1; off < 256; off <<= 1) {
        int add = (threadIdx.x >= (unsigned)off) ? sh[threadIdx.x - off] : 0;
        __syncthreads();
        sh[threadIdx.x] += add;
        __syncthreads();
    }
    if (threadIdx.x < (unsigned)nb) bsum[threadIdx.x] = sh[threadIdx.x] - v;
}

__global__ void k_scan_c(const int* __restrict__ deg, const int* __restrict__ bsum,
                         int* __restrict__ offs, int* __restrict__ cursor, int N) {
    __shared__ int sh[256];
    int i = blockIdx.x * 256 + threadIdx.x;
    int v = (i < N) ? deg[i] : 0;
    sh[threadIdx.x] = v;
    __syncthreads();
    for (int off = 1; off < 256; off <<= 1) {
        int add = (threadIdx.x >= (unsigned)off) ? sh[threadIdx.x - off] : 0;
        __syncthreads();
        sh[threadIdx.x] += add;
        __syncthreads();
    }
    int ex = bsum[blockIdx.x] + sh[threadIdx.x] - v;
    if (i < N) { offs[i] = ex; cursor[i] = ex; }
    if (i == N - 1) offs[N] = ex + v;
}

__global__ void k_scatter(const int* __restrict__ src, const int* __restrict__ dst,
                          int* cursor, int* __restrict__ eord,
                          int* __restrict__ srco, int E) {
    int e = blockIdx.x * 256 + threadIdx.x;
    if (e < E) {
        int d = dst[e];
        int p = atomicAdd(&cursor[d], 1);
        eord[p] = e;
        srco[p] = src[e];
    }
}

__global__ void k_eaord(const int* __restrict__ eord, const float* __restrict__ ea,
                        float4* __restrict__ ea3o, int E) {
    int idx = blockIdx.x * 256 + threadIdx.x;
    if (idx >= E) return;
    int e = eord[idx];
    float4 q;
    q.x = ea[e * 3 + 0]; q.y = ea[e * 3 + 1]; q.z = ea[e * 3 + 2]; q.w = 0.f;
    ea3o[idx] = q;
}

__global__ void k_bstart(const int* __restrict__ batch, int* __restrict__ boffs, int N, int B) {
    int n = blockIdx.x * 256 + threadIdx.x;
    if (n >= N) return;
    int b1 = batch[n];
    if (n == 0) for (int b = 0; b <= b1; ++b) boffs[b] = 0;
    int b2 = (n + 1 < N) ? batch[n + 1] : B;
    for (int b = b1 + 1; b <= b2; ++b) boffs[b] = n + 1;
}

// ---------------------------------------------------------------- per-node linear + attention dots (fused)
__global__ __launch_bounds__(256) void k_node_lin(const float* __restrict__ h,
                           const float* __restrict__ linw, const float* __restrict__ linb,
                           const float* __restrict__ attw, const float* __restrict__ attb,
                           float* __restrict__ A1, float* __restrict__ A2,
                           float* __restrict__ a1, float* __restrict__ a2, int N) {
    __shared__ float hT[HID][12];
    int nb = blockIdx.x * 8;
    int tid = threadIdx.x;
    for (int i = tid; i < 8 * HID; i += 256) {
        int n = i >> 7, c = i & 127;
        int gn = nb + n;
        hT[c][n] = (gn < N) ? h[gn * HID + c] : 0.f;
    }
    __syncthreads();
    // attention dots: 8 nodes x 32 lanes
    {
        int node = tid >> 5, lane32 = tid & 31;
        float p1 = 0.f, p2 = 0.f;
#pragma unroll
        for (int j = 0; j < 4; ++j) {
            int k = lane32 * 4 + j;
            float hv = hT[k][node];
            p1 += hv * attw[k];
            p2 += hv * attw[128 + k];
        }
        for (int off = 16; off > 0; off >>= 1) {
            p1 += __shfl_down(p1, off, 32);
            p2 += __shfl_down(p2, off, 32);
        }
        int gn = nb + node;
        if (lane32 == 0 && gn < N) {
            a1[gn] = p1 + attb[0];
            a2[gn] = p2;
        }
    }
    int c = tid & 127, r = tid >> 7;
    const float* Wd = linw;
    const float* Ws = linw + 128 * HID;
    float acc1[4] = {0, 0, 0, 0}, acc2[4] = {0, 0, 0, 0};
#pragma unroll 4
    for (int k = 0; k < HID; ++k) {
        float wd = Wd[k * HID + c];
        float ws = Ws[k * HID + c];
        float4 hv = *(const float4*)&hT[k][r * 4];
        acc1[0] += hv.x * wd; acc2[0] += hv.x * ws;
        acc1[1] += hv.y * wd; acc2[1] += hv.y * ws;
        acc1[2] += hv.z * wd; acc2[2] += hv.z * ws;
        acc1[3] += hv.w * wd; acc2[3] += hv.w * ws;
    }
#pragma unroll
    for (int j = 0; j < 4; ++j) {
        int gn = nb + r * 4 + j;
        if (gn < N) {
            A1[gn * HID + c] = acc1[j] + linb[c];
            A2[gn * HID + c] = acc2[j];
        }
    }
}

// ---------------------------------------------------------------- edge conv (CSR, 8 slots, float4, alpha fused)
// also zeroes the bn stats buffer (block 0) so no memset dispatch is needed
__global__ __launch_bounds__(256) void k_edge(const float* __restrict__ A1,
        const float* __restrict__ A2, const float* __restrict__ a1,
        const float* __restrict__ a2, const int* __restrict__ srco,
        const float4* __restrict__ ea3o, const int* __restrict__ offs,
        const float* __restrict__ linw3, const float* __restrict__ attw3,
        float* __restrict__ hconv, double* __restrict__ stats, int N) {
    __shared__ float w3s[3 * HID];
    __shared__ float aw3s[3];
    __shared__ float part[8][HID];
    int n = blockIdx.x;
    int tid = threadIdx.x;        // 256 threads = 8 edge slots x 32 lanes x 4 channels
    if (n == 0) stats[tid] = 0.0;
    int lane32 = tid & 31, slot = tid >> 5;
    int c4 = lane32 * 4;
    for (int i = tid; i < 3 * HID; i += 256) w3s[i] = linw3[i];
    if (tid < 3) aw3s[tid] = attw3[tid];
    __syncthreads();
    float4 w0v = *(const float4*)&w3s[c4];
    float4 w1v = *(const float4*)&w3s[HID + c4];
    float4 w2v = *(const float4*)&w3s[2 * HID + c4];
    float aw0 = aw3s[0], aw1 = aw3s[1], aw2 = aw3s[2];
    float a1n = a1[n];
    float4 A1v = *(const float4*)&A1[(size_t)n * HID + c4];
    float4 acc; acc.x = acc.y = acc.z = acc.w = 0.f;
    int s0 = offs[n], s1 = offs[n + 1];
    for (int idx = s0 + slot; idx < s1; idx += 8) {
        int s = srco[idx];
        float4 q = ea3o[idx];
        float logit = a1n + a2[s] + q.x * aw0 + q.y * aw1 + q.z * aw2;
        float al = 1.f / (1.f + __expf(-logit));
        float4 a2v = *(const float4*)&A2[(size_t)s * HID + c4];
        float4 pre;
        pre.x = A1v.x + a2v.x + q.x * w0v.x + q.y * w1v.x + q.z * w2v.x;
        pre.y = A1v.y + a2v.y + q.x * w0v.y + q.y * w1v.y + q.z * w2v.y;
        pre.z = A1v.z + a2v.z + q.x * w0v.z + q.y * w1v.z + q.z * w2v.z;
        pre.w = A1v.w + a2v.w + q.x * w0v.w + q.y * w1v.w + q.z * w2v.w;
        acc.x += al * pre.x; acc.y += al * pre.y;
        acc.z += al * pre.z; acc.w += al * pre.w;
    }
    *(float4*)&part[slot][c4] = acc;
    __syncthreads();
    for (int st = 4; st >= 1; st >>= 1) {
        if (slot < st) {
            float4 p = *(const float4*)&part[slot][c4];
            float4 r = *(const float4*)&part[slot + st][c4];
            p.x += r.x; p.y += r.y; p.z += r.z; p.w += r.w;
            *(float4*)&part[slot][c4] = p;
        }
        __syncthreads();
    }
    if (slot == 0) *(float4*)&hconv[(size_t)n * HID + c4] = *(const float4*)&part[0][c4];
}

// ---------------------------------------------------------------- Fourier-Kolmogorov GEMM (split-f16 MFMA)
// K-split 4 (K=256/block). Trig computed ONCE per block into padded LDS planes
// (2 barriers total), then a barrier-free ds_read+global-B+MFMA stream.
#define FK_LDSH 132        // floats per hsh row (128 + 4 pad)
#define FK_AST  264        // f16 per staged-A row (256 + 8 pad) = 528 B, 16B-aligned
__global__ __launch_bounds__(256) void k_fk(const float* __restrict__ h,
        const _Float16* __restrict__ whi, const _Float16* __restrict__ wlo,
        float* __restrict__ p0, float* __restrict__ p1,
        float* __restrict__ p2, float* __restrict__ p3, int N) {
    __shared__ float hsh[32 * FK_LDSH];
    __shared__ _Float16 ahi[32 * FK_AST];
    __shared__ _Float16 alo[32 * FK_AST];
    int tid = threadIdx.x;
    int bx = blockIdx.x;
    int nb = (bx >> 2) * 32;
    int ks = bx & 3;
    int kbase = ks * 256;
    for (int i = tid; i < 32 * 32; i += 256) {
        int nn = i >> 5, c4 = (i & 31) * 4;
        int gn = nb + nn;
        float4 v = (gn < N) ? *(const float4*)&h[gn * HID + c4] : make_float4(0.f, 0.f, 0.f, 0.f);
        *(float4*)&hsh[nn * FK_LDSH + c4] = v;
    }
    __syncthreads();
    // trig once: 32 rows x 256 k. thread t: row = t>>3, octets {t&7 + 8i}
    {
        int row = tid >> 3;
        const float* hrow = &hsh[row * FK_LDSH];
#pragma unroll
        for (int i = 0; i < 4; ++i) {
            int oct = (tid & 7) + 8 * i;
            int kg = kbase + oct * 8;
            int fr = kg >> 7, ii = kg & 127;
            float freqf = 6.2831853f * (float)(fr + 1);
            float4 h0 = *(const float4*)&hrow[ii];
            float4 h1 = *(const float4*)&hrow[ii + 4];
            float hv[8] = {h0.x, h0.y, h0.z, h0.w, h1.x, h1.y, h1.z, h1.w};
            half8 vh, vl;
#pragma unroll
            for (int j = 0; j < 8; ++j) {
                float ang = freqf * hv[j] + 0.78539816f;
                float a = 1.41421356f * __sinf(ang);   // sin + cos
                _Float16 hi = (_Float16)a;
                vh[j] = hi;
                vl[j] = (_Float16)((a - (float)hi) * 2048.f);
            }
            *(half8*)&ahi[row * FK_AST + oct * 8] = vh;
            *(half8*)&alo[row * FK_AST + oct * 8] = vl;
        }
    }
    __syncthreads();
    int lane = tid & 63, wv = tid >> 6;
    int quad = lane >> 4, l16 = lane & 15;
    int n0w = wv * 32;
    f4 acc0[2][2], accL[2][2];
#pragma unroll
    for (int mi = 0; mi < 2; ++mi)
#pragma unroll
        for (int ni = 0; ni < 2; ++ni) { acc0[mi][ni] = (f4)(0.f); accL[mi][ni] = (f4)(0.f); }
    const _Float16* bhp0 = whi + (size_t)(n0w + l16) * 1024 + kbase + quad * 8;
    const _Float16* bhp1 = whi + (size_t)(n0w + 16 + l16) * 1024 + kbase + quad * 8;
    const _Float16* blp0 = wlo + (size_t)(n0w + l16) * 1024 + kbase + quad * 8;
    const _Float16* blp1 = wlo + (size_t)(n0w + 16 + l16) * 1024 + kbase + quad * 8;
#pragma unroll 2
    for (int step = 0; step < 8; ++step) {
        int ka = step * 32 + quad * 8;
        half8 ah0 = *(const half8*)&ahi[l16 * FK_AST + ka];
        half8 ah1 = *(const half8*)&ahi[(l16 + 16) * FK_AST + ka];
        half8 al0 = *(const half8*)&alo[l16 * FK_AST + ka];
        half8 al1 = *(const half8*)&alo[(l16 + 16) * FK_AST + ka];
        int ko = step * 32;
        half8 bh0 = *(const half8*)(bhp0 + ko);
        half8 bh1 = *(const half8*)(bhp1 + ko);
        half8 bl0 = *(const half8*)(blp0 + ko);
        half8 bl1 = *(const half8*)(blp1 + ko);
        acc0[0][0] = __builtin_amdgcn_mfma_f32_16x16x32_f16(ah0, bh0, acc0[0][0], 0, 0, 0);
        acc0[0][1] = __builtin_amdgcn_mfma_f32_16x16x32_f16(ah0, bh1, acc0[0][1], 0, 0, 0);
        acc0[1][0] = __builtin_amdgcn_mfma_f32_16x16x32_f16(ah1, bh0, acc0[1][0], 0, 0, 0);
        acc0[1][1] = __builtin_amdgcn_mfma_f32_16x16x32_f16(ah1, bh1, acc0[1][1], 0, 0, 0);
        accL[0][0] = __builtin_amdgcn_mfma_f32_16x16x32_f16(ah0, bl0, accL[0][0], 0, 0, 0);
        accL[0][1] = __builtin_amdgcn_mfma_f32_16x16x32_f16(ah0, bl1, accL[0][1], 0, 0, 0);
        accL[1][0] = __builtin_amdgcn_mfma_f32_16x16x32_f16(ah1, bl0, accL[1][0], 0, 0, 0);
        accL[1][1] = __builtin_amdgcn_mfma_f32_16x16x32_f16(ah1, bl1, accL[1][1], 0, 0, 0);
        accL[0][0] = __builtin_amdgcn_mfma_f32_16x16x32_f16(al0, bh0, accL[0][0], 0, 0, 0);
        accL[0][1] = __builtin_amdgcn_mfma_f32_16x16x32_f16(al0, bh1, accL[0][1], 0, 0, 0);
        accL[1][0] = __builtin_amdgcn_mfma_f32_16x16x32_f16(al1, bh0, accL[1][0], 0, 0, 0);
        accL[1][1] = __builtin_amdgcn_mfma_f32_16x16x32_f16(al1, bh1, accL[1][1], 0, 0, 0);
    }
    float* p = (ks == 0) ? p0 : (ks == 1) ? p1 : (ks == 2) ? p2 : p3;
    const float inv = 1.0f / 2048.0f;
#pragma unroll
    for (int mi = 0; mi < 2; ++mi)
#pragma unroll
        for (int ni = 0; ni < 2; ++ni)
#pragma unroll
            for (int r = 0; r < 4; ++r) {
                int gn = nb + mi * 16 + quad * 4 + r;
                if (gn < N)
                    p[gn * HID + n0w + ni * 16 + l16] = acc0[mi][ni][r] + accL[mi][ni][r] * inv;
            }
}

// ---------------------------------------------------------------- batchnorm stats (5 streams)
__global__ void k_bn_stats(float* __restrict__ hconv,
                           const float* __restrict__ p0, const float* __restrict__ p1,
                           const float* __restrict__ p2, const float* __restrict__ p3,
                           const float* __restrict__ fkb,
                           double* __restrict__ stats, int N) {
    int c = threadIdx.x & 127, half = threadIdx.x >> 7;
    float bias = fkb[c];
    float s = 0.f, s2 = 0.f;
    for (int n = blockIdx.x * 2 + half; n < N; n += gridDim.x * 2) {
        int idx = n * HID + c;
        float v = hconv[idx] + p0[idx] + p1[idx] + p2[idx] + p3[idx] + bias;
        hconv[idx] = v;
        s += v; s2 += v * v;
    }
    __shared__ float sh[256], sh2[256];
    sh[threadIdx.x] = s; sh2[threadIdx.x] = s2;
    __syncthreads();
    if (half == 0) {
        s = sh[c] + sh[128 + c];
        s2 = sh2[c] + sh2[128 + c];
        atomicAdd(&stats[c], (double)s);
        atomicAdd(&stats[128 + c], (double)s2);
    }
}

// bn_final folded in; optionally computes pool scores (last layer)
__global__ void k_bn_apply(const float* __restrict__ hsum, const double* __restrict__ stats,
                           const float* __restrict__ g, const float* __restrict__ b,
                           const float* __restrict__ pw, const float* __restrict__ pb,
                           float* __restrict__ h, float* __restrict__ s,
                           int do_score, int N) {
    __shared__ float red[4];
    int idx = blockIdx.x * 256 + threadIdx.x;
    int valid = idx < N * HID;
    int c = idx & 127;
    double invN = 1.0 / (double)N;
    float mu = (float)(stats[c] * invN);
    float var = (float)(stats[128 + c] * invN) - mu * mu;
    float inv = 1.f / sqrtf(var + 1e-5f);
    float sc = g[c] * inv;
    float sh = b[c] - mu * sc;
    float o = 0.f;
    if (valid) {
        o = fmaxf(hsum[idx] * sc + sh, 0.f);
        h[idx] = o;
    }
    if (do_score) {
        float p = valid ? o * pw[c] : 0.f;
        for (int off = 32; off > 0; off >>= 1) p += __shfl_down(p, off);
        int wid = threadIdx.x >> 6;
        if ((threadIdx.x & 63) == 0) red[wid] = p;
        __syncthreads();
        int row = idx >> 7;
        int half = threadIdx.x >> 7;
        if ((threadIdx.x & 127) == 0 && row < N)
            s[row] = red[half * 2] + red[half * 2 + 1] + pb[0];
    }
}

// ---------------------------------------------------------------- softmax partials
__global__ void k_smax1(const float* __restrict__ s, float* __restrict__ mzp, int N) {
    __shared__ float red[256];
    float m = -INFINITY;
    for (int n = blockIdx.x * 256 + threadIdx.x; n < N; n += SMAXB * 256)
        m = fmaxf(m, s[n]);
    red[threadIdx.x] = m;
    __syncthreads();
    for (int off = 128; off > 0; off >>= 1) {
        if (threadIdx.x < (unsigned)off)
            red[threadIdx.x] = fmaxf(red[threadIdx.x], red[threadIdx.x + off]);
        __syncthreads();
    }
    m = red[0];
    __syncthreads();
    float z = 0.f;
    for (int n = blockIdx.x * 256 + threadIdx.x; n < N; n += SMAXB * 256)
        z += __expf(s[n] - m);
    red[threadIdx.x] = z;
    __syncthreads();
    for (int off = 128; off > 0; off >>= 1) {
        if (threadIdx.x < (unsigned)off) red[threadIdx.x] += red[threadIdx.x + off];
        __syncthreads();
    }
    if (threadIdx.x == 0) { mzp[blockIdx.x * 2] = m; mzp[blockIdx.x * 2 + 1] = red[0]; }
}

__device__ __forceinline__ void combine_mz(const float* mzp, float& m, float& Z) {
    m = -INFINITY;
#pragma unroll 8
    for (int i = 0; i < SMAXB; ++i) m = fmaxf(m, mzp[i * 2]);
    Z = 0.f;
#pragma unroll 8
    for (int i = 0; i < SMAXB; ++i) Z += mzp[i * 2 + 1] * __expf(mzp[i * 2] - m);
}

// ---------------------------------------------------------------- attention pool (split)
__global__ void k_pool_part(const float* __restrict__ h, const float* __restrict__ s,
                            const float* __restrict__ mzp, const int* __restrict__ boffs,
                            float* __restrict__ part) {
    int b = blockIdx.x >> 4, split = blockIdx.x & (PSPLIT - 1);
    int c = threadIdx.x & 127, half = threadIdx.x >> 7;
    float m, Z;
    combine_mz(mzp, m, Z);
    (void)Z;
    int n0 = boffs[b], n1 = boffs[b + 1];
    float acc = 0.f;
    for (int n = n0 + split * 2 + half; n < n1; n += PSPLIT * 2)
        acc += __expf(s[n] - m) * h[n * HID + c];
    __shared__ float prt[2][HID];
    prt[half][c] = acc;
    __syncthreads();
    if (half == 0) part[(size_t)(b * PSPLIT + split) * HID + c] = prt[0][c] + prt[1][c];
}

__global__ void k_pool_sum(const float* __restrict__ part, const float* __restrict__ mzp,
                           float* __restrict__ pooled) {
    int b = blockIdx.x, c = threadIdx.x;
    float m, Z;
    combine_mz(mzp, m, Z);
    float acc = 0.f;
#pragma unroll
    for (int i = 0; i < PSPLIT; ++i) acc += part[(size_t)(b * PSPLIT + i) * HID + c];
    pooled[b * HID + c] = acc / Z;
}

// ---------------------------------------------------------------- heads (grid = B*4)
__global__ __launch_bounds__(256) void k_head(const float* __restrict__ pooled,
                       const float* __restrict__ sg_table,
                       const int* __restrict__ space_group,
                       const float* __restrict__ hw1, const float* __restrict__ hb1,
                       const float* __restrict__ ew2, const float* __restrict__ eb2,
                       const float* __restrict__ sw2, const float* __restrict__ sb2,
                       const float* __restrict__ cw2, const float* __restrict__ cb2,
                       const float* __restrict__ mw2, const float* __restrict__ mb2,
                       float* __restrict__ out, int B) {
    __shared__ float comb[256];
    __shared__ float zred[2][128];
    __shared__ float zsh[128];
    int b = blockIdx.x >> 2, i = blockIdx.x & 3;
    int t = threadIdx.x;
    comb[t] = (t < 128) ? pooled[b * HID + t] : sg_table[space_group[b] * HID + (t - 128)];
    __syncthreads();
    int half = t >> 7, tt = t & 127;
    const float* W = hw1 + ((size_t)i * 256 + half * 128) * HID;
    const float* cb = &comb[half * 128];
    float z = 0.f;
#pragma unroll 8
    for (int k = 0; k < 128; ++k) z += cb[k] * W[k * HID + tt];
    zred[half][tt] = z;
    __syncthreads();
    if (t < 128) zsh[t] = fmaxf(zred[0][t] + zred[1][t] + hb1[i * HID + t], 0.f);
    __syncthreads();
    const int od[4] = {1, 3, 7, 3};
    const int base[4] = {0, 64, 256, 704};
    const float* w2 = (i == 0) ? ew2 : (i == 1) ? sw2 : (i == 2) ? cw2 : mw2;
    const float* b2 = (i == 0) ? eb2 : (i == 1) ? sb2 : (i == 2) ? cb2 : mb2;
    int odi = od[i];
    if (t < odi) {
        float o = b2[t];
        for (int c = 0; c < HID; ++c) o += zsh[c] * w2[c * odi + t];
        out[base[i] + b * odi + t] = o;
    }
}

// ---------------------------------------------------------------- launch
extern "C" void kernel_launch(void* const* d_in, const int* in_sizes, int n_in,
                              void* d_out, int out_size, void* d_ws, size_t ws_size,
                              hipStream_t stream) {
    const float* x          = (const float*)d_in[0];
    const int*   edge_index = (const int*)d_in[1];
    const float* edge_attr  = (const float*)d_in[2];
    const int*   batch      = (const int*)d_in[3];
    const int*   space_group= (const int*)d_in[4];
    const float* node_w     = (const float*)d_in[5];
    const float* node_b     = (const float*)d_in[6];
    const float* sg_table   = (const float*)d_in[7];
    const float* lin_w      = (const float*)d_in[8];
    const float* lin_b      = (const float*)d_in[9];
    const float* att_w      = (const float*)d_in[10];
    const float* att_b      = (const float*)d_in[11];
    const float* fk_w       = (const float*)d_in[12];
    const float* fk_b       = (const float*)d_in[13];
    const float* bn_g       = (const float*)d_in[14];
    const float* bn_b       = (const float*)d_in[15];
    const float* pool_w     = (const float*)d_in[16];
    const float* pool_b     = (const float*)d_in[17];
    const float* head_w1    = (const float*)d_in[18];
    const float* head_b1    = (const float*)d_in[19];
    const float* ew2 = (const float*)d_in[20]; const float* eb2 = (const float*)d_in[21];
    const float* sw2 = (const float*)d_in[22]; const float* sb2 = (const float*)d_in[23];
    const float* cw2 = (const float*)d_in[24]; const float* cb2 = (const float*)d_in[25];
    const float* mw2 = (const float*)d_in[26]; const float* mb2 = (const float*)d_in[27];
    float* out = (float*)d_out;

    const int N = in_sizes[3];
    const int E = in_sizes[1] / 2;
    const int B = in_sizes[4];
    const int* src = edge_index;
    const int* dst = edge_index + E;

    char* w = (char*)d_ws;
    auto alloc = [&](size_t bytes) { char* p = w; w += (bytes + 255) & ~(size_t)255; return p; };
    float*  h      = (float*)alloc((size_t)N * HID * 4);
    float*  A1     = (float*)alloc((size_t)N * HID * 4);  // reused as FK partial 0
    float*  A2     = (float*)alloc((size_t)N * HID * 4);  // reused as FK partial 1
    float*  p2     = (float*)alloc((size_t)N * HID * 4);  // FK partial 2
    float*  p3     = (float*)alloc((size_t)N * HID * 4);  // FK partial 3
    float*  hconv  = (float*)alloc((size_t)N * HID * 4);  // becomes pre-BN sum in place
    float*  a1     = (float*)alloc((size_t)N * 4);
    float*  a2     = (float*)alloc((size_t)N * 4);
    float*  sbuf   = (float*)alloc((size_t)N * 4);
    int*    deg    = (int*)alloc((size_t)N * 4);
    int*    cursor = (int*)alloc((size_t)N * 4);
    int*    offs   = (int*)alloc((size_t)(N + 1) * 4);
    int*    eord   = (int*)alloc((size_t)E * 4);
    int*    srco   = (int*)alloc((size_t)E * 4);
    float4* ea3o   = (float4*)alloc((size_t)E * 16);
    _Float16* whi  = (_Float16*)alloc((size_t)DEPTH * 1024 * HID * 2);
    _Float16* wlo  = (_Float16*)alloc((size_t)DEPTH * 1024 * HID * 2);
    int*    bsum   = (int*)alloc(256 * 4);
    int*    boffs  = (int*)alloc((size_t)(B + 1) * 4);
    double* stats  = (double*)alloc(256 * 8);
    float*  mzp    = (float*)alloc(SMAXB * 2 * 4);
    float*  part   = (float*)alloc((size_t)B * PSPLIT * HID * 4);
    float*  pooled = (float*)alloc((size_t)B * HID * 4);

    const int nchunk = (N + 255) / 256;
    const int echunk = (E + 255) / 256;

    // one-time per launch: W split + CSR build
    k_wsplit<<<128, 256, 0, stream>>>(fk_w, whi, wlo);
    hipMemsetAsync(deg, 0, (size_t)N * 4, stream);
    k_hist<<<echunk, 256, 0, stream>>>(dst, deg, E);
    k_scan_a<<<nchunk, 256, 0, stream>>>(deg, bsum, N);
    k_scan_b<<<1, 256, 0, stream>>>(bsum, nchunk);
    k_scan_c<<<nchunk, 256, 0, stream>>>(deg, bsum, offs, cursor, N);
    k_scatter<<<echunk, 256, 0, stream>>>(src, dst, cursor, eord, srco, E);
    k_eaord<<<echunk, 256, 0, stream>>>(eord, edge_attr, ea3o, E);
    k_bstart<<<nchunk, 256, 0, stream>>>(batch, boffs, N, B);

    k_node_embed<<<(N * HID + 255) / 256, 256, 0, stream>>>(x, node_w, node_b, h, N);

    for (int l = 0; l < DEPTH; ++l) {
        const float* linw_l = lin_w + (size_t)l * 259 * HID;
        k_node_lin<<<(N + 7) / 8, 256, 0, stream>>>(
            h, linw_l, lin_b + l * HID, att_w + (size_t)l * 259, att_b + l,
            A1, A2, a1, a2, N);
        k_edge<<<N, 256, 0, stream>>>(A1, A2, a1, a2, srco, ea3o, offs,
                                      linw_l + 256 * HID, att_w + (size_t)l * 259 + 256,
                                      hconv, stats, N);
        k_fk<<<((N + 31) / 32) * 4, 256, 0, stream>>>(
            h, whi + (size_t)l * 131072, wlo + (size_t)l * 131072, A1, A2, p2, p3, N);
        k_bn_stats<<<200, 256, 0, stream>>>(hconv, A1, A2, p2, p3, fk_b + l * HID, stats, N);
        k_bn_apply<<<(N * HID + 255) / 256, 256, 0, stream>>>(
            hconv, stats, bn_g + l * HID, bn_b + l * HID, pool_w, pool_b,
            h, sbuf, (l == DEPTH - 1) ? 1 : 0, N);
    }

    k_smax1<<<SMAXB, 256, 0, stream>>>(sbuf, mzp, N);
    k_pool_part<<<B * PSPLIT, 256, 0, stream>>>(h, sbuf, mzp, boffs, part);
    k_pool_sum<<<B, 128, 0, stream>>>(part, mzp, pooled);
    k_head<<<B * 4, 256, 0, stream>>>(pooled, sg_table, space_group, head_w1, head_b1,
                                      ew2, eb2, sw2, sb2, cw2, cb2, mw2, mb2, out, B);
}

// Round 11
// 779.504 us; speedup vs baseline: 1.3815x; 1.0510x over previous
//
#include <hip/hip_runtime.h>
#include <math.h>

#define HID 128
#define DEPTH 4
#define PSPLIT 16
#define SMAXB 40

typedef _Float16 half8 __attribute__((ext_vector_type(8)));
typedef float f4 __attribute__((ext_vector_type(4)));

// ---------------------------------------------------------------- node embed
__global__ void k_node_embed(const float* __restrict__ x, const float* __restrict__ nw,
                             const float* __restrict__ nb, float* __restrict__ h, int N) {
    int idx = blockIdx.x * blockDim.x + threadIdx.x;
    if (idx >= N * HID) return;
    int n = idx >> 7, c = idx & 127;
    float acc = nb[c];
#pragma unroll
    for (int d = 0; d < 4; ++d) acc += x[n * 4 + d] * nw[d * HID + c];
    h[idx] = acc;
}

// ---------------------------------------------------------------- W split+transpose (once per launch)
__global__ void k_wsplit(const float* __restrict__ fkw, _Float16* __restrict__ whi,
                         _Float16* __restrict__ wlo) {
    __shared__ float sh[64][65];
    int bid = blockIdx.x;           // 4 layers * 16 kblk * 2 nblk = 128 blocks
    int l = bid >> 5; int r = bid & 31; int kb = r >> 1; int nbk = r & 1;
    const float* W = fkw + (size_t)l * 131072;
    _Float16* Hl = whi + (size_t)l * 131072;
    _Float16* Ll = wlo + (size_t)l * 131072;
    int k0 = kb * 64, n0 = nbk * 64;
    for (int i = threadIdx.x; i < 4096; i += 256) {
        int kk = i >> 6, nn = i & 63;
        sh[kk][nn] = W[(k0 + kk) * HID + n0 + nn];
    }
    __syncthreads();
    for (int i = threadIdx.x; i < 4096; i += 256) {
        int nn = i >> 6, kk = i & 63;
        float w = sh[kk][nn];
        _Float16 hi = (_Float16)w;
        _Float16 lo = (_Float16)((w - (float)hi) * 2048.f);
        Hl[(n0 + nn) * 1024 + k0 + kk] = hi;
        Ll[(n0 + nn) * 1024 + k0 + kk] = lo;
    }
}

// ---------------------------------------------------------------- CSR build
__global__ void k_hist(const int* __restrict__ dst, int* __restrict__ deg, int E) {
    int e = blockIdx.x * 256 + threadIdx.x;
    if (e < E) atomicAdd(&deg[dst[e]], 1);
}

__global__ void k_scan_a(const int* __restrict__ deg, int* __restrict__ bsum, int N) {
    __shared__ int sh[256];
    int i = blockIdx.x * 256 + threadIdx.x;
    sh[threadIdx.x] = (i < N) ? deg[i] : 0;
    __syncthreads();
    for (int off = 128; off > 0; off >>= 1) {
        if (threadIdx.x < (unsigned)off) sh[threadIdx.x] += sh[threadIdx.x + off];
        __syncthreads();
    }
    if (threadIdx.x == 0) bsum[blockIdx.x] = sh[0];
}

__global__ void k_scan_b(int* __restrict__ bsum, int nb) {
    __shared__ int sh[256];
    int v = (threadIdx.x < (unsigned)nb) ? bsum[threadIdx.x] : 0;
    sh[threadIdx.x] = v;
    __syncthreads();
    for (int off = 1; off < 256; off <<= 1) {
        int add = (threadIdx.x >= (unsigned)off) ? sh[threadIdx.x - off] : 0;
        __syncthreads();
        sh[threadIdx.x] += add;
        __syncthreads();
    }
    if (threadIdx.x < (unsigned)nb) bsum[threadIdx.x] = sh[threadIdx.x] - v;
}

__global__ void k_scan_c(const int* __restrict__ deg, const int* __restrict__ bsum,
                         int* __restrict__ offs, int* __restrict__ cursor, int N) {
    __shared__ int sh[256];
    int i = blockIdx.x * 256 + threadIdx.x;
    int v = (i < N) ? deg[i] : 0;
    sh[threadIdx.x] = v;
    __syncthreads();
    for (int off = 1; off < 256; off <<= 1) {
        int add = (threadIdx.x >= (unsigned)off) ? sh[threadIdx.x - off] : 0;
        __syncthreads();
        sh[threadIdx.x] += add;
        __syncthreads();
    }
    int ex = bsum[blockIdx.x] + sh[threadIdx.x] - v;
    if (i < N) { offs[i] = ex; cursor[i] = ex; }
    if (i == N - 1) offs[N] = ex + v;
}

__global__ void k_scatter(const int* __restrict__ src, const int* __restrict__ dst,
                          int* cursor, int* __restrict__ eord,
                          int* __restrict__ srco, int E) {
    int e = blockIdx.x * 256 + threadIdx.x;
    if (e < E) {
        int d = dst[e];
        int p = atomicAdd(&cursor[d], 1);
        eord[p] = e;
        srco[p] = src[e];
    }
}

__global__ void k_eaord(const int* __restrict__ eord, const float* __restrict__ ea,
                        float4* __restrict__ ea3o, int E) {
    int idx = blockIdx.x * 256 + threadIdx.x;
    if (idx >= E) return;
    int e = eord[idx];
    float4 q;
    q.x = ea[e * 3 + 0]; q.y = ea[e * 3 + 1]; q.z = ea[e * 3 + 2]; q.w = 0.f;
    ea3o[idx] = q;
}

__global__ void k_bstart(const int* __restrict__ batch, int* __restrict__ boffs, int N, int B) {
    int n = blockIdx.x * 256 + threadIdx.x;
    if (n >= N) return;
    int b1 = batch[n];
    if (n == 0) for (int b = 0; b <= b1; ++b) boffs[b] = 0;
    int b2 = (n + 1 < N) ? batch[n + 1] : B;
    for (int b = b1 + 1; b <= b2; ++b) boffs[b] = n + 1;
}

// ---------------------------------------------------------------- per-node linear + attention dots (fused)
__global__ __launch_bounds__(256) void k_node_lin(const float* __restrict__ h,
                           const float* __restrict__ linw, const float* __restrict__ linb,
                           const float* __restrict__ attw, const float* __restrict__ attb,
                           float* __restrict__ A1, float* __restrict__ A2,
                           float* __restrict__ a1, float* __restrict__ a2, int N) {
    __shared__ float hT[HID][12];
    int nb = blockIdx.x * 8;
    int tid = threadIdx.x;
    for (int i = tid; i < 8 * HID; i += 256) {
        int n = i >> 7, c = i & 127;
        int gn = nb + n;
        hT[c][n] = (gn < N) ? h[gn * HID + c] : 0.f;
    }
    __syncthreads();
    // attention dots: 8 nodes x 32 lanes
    {
        int node = tid >> 5, lane32 = tid & 31;
        float p1 = 0.f, p2 = 0.f;
#pragma unroll
        for (int j = 0; j < 4; ++j) {
            int k = lane32 * 4 + j;
            float hv = hT[k][node];
            p1 += hv * attw[k];
            p2 += hv * attw[128 + k];
        }
        for (int off = 16; off > 0; off >>= 1) {
            p1 += __shfl_down(p1, off, 32);
            p2 += __shfl_down(p2, off, 32);
        }
        int gn = nb + node;
        if (lane32 == 0 && gn < N) {
            a1[gn] = p1 + attb[0];
            a2[gn] = p2;
        }
    }
    int c = tid & 127, r = tid >> 7;
    const float* Wd = linw;
    const float* Ws = linw + 128 * HID;
    float acc1[4] = {0, 0, 0, 0}, acc2[4] = {0, 0, 0, 0};
#pragma unroll 4
    for (int k = 0; k < HID; ++k) {
        float wd = Wd[k * HID + c];
        float ws = Ws[k * HID + c];
        float4 hv = *(const float4*)&hT[k][r * 4];
        acc1[0] += hv.x * wd; acc2[0] += hv.x * ws;
        acc1[1] += hv.y * wd; acc2[1] += hv.y * ws;
        acc1[2] += hv.z * wd; acc2[2] += hv.z * ws;
        acc1[3] += hv.w * wd; acc2[3] += hv.w * ws;
    }
#pragma unroll
    for (int j = 0; j < 4; ++j) {
        int gn = nb + r * 4 + j;
        if (gn < N) {
            A1[gn * HID + c] = acc1[j] + linb[c];
            A2[gn * HID + c] = acc2[j];
        }
    }
}

// ---------------------------------------------------------------- edge conv (CSR, 8 slots, float4, alpha fused)
// also zeroes the bn stats buffer (block 0) so no memset dispatch is needed
__global__ __launch_bounds__(256) void k_edge(const float* __restrict__ A1,
        const float* __restrict__ A2, const float* __restrict__ a1,
        const float* __restrict__ a2, const int* __restrict__ srco,
        const float4* __restrict__ ea3o, const int* __restrict__ offs,
        const float* __restrict__ linw3, const float* __restrict__ attw3,
        float* __restrict__ hconv, double* __restrict__ stats, int N) {
    __shared__ float w3s[3 * HID];
    __shared__ float aw3s[3];
    __shared__ float part[8][HID];
    int n = blockIdx.x;
    int tid = threadIdx.x;        // 256 threads = 8 edge slots x 32 lanes x 4 channels
    if (n == 0) stats[tid] = 0.0;
    int lane32 = tid & 31, slot = tid >> 5;
    int c4 = lane32 * 4;
    for (int i = tid; i < 3 * HID; i += 256) w3s[i] = linw3[i];
    if (tid < 3) aw3s[tid] = attw3[tid];
    __syncthreads();
    float4 w0v = *(const float4*)&w3s[c4];
    float4 w1v = *(const float4*)&w3s[HID + c4];
    float4 w2v = *(const float4*)&w3s[2 * HID + c4];
    float aw0 = aw3s[0], aw1 = aw3s[1], aw2 = aw3s[2];
    float a1n = a1[n];
    float4 A1v = *(const float4*)&A1[(size_t)n * HID + c4];
    float4 acc; acc.x = acc.y = acc.z = acc.w = 0.f;
    int s0 = offs[n], s1 = offs[n + 1];
    for (int idx = s0 + slot; idx < s1; idx += 8) {
        int s = srco[idx];
        float4 q = ea3o[idx];
        float logit = a1n + a2[s] + q.x * aw0 + q.y * aw1 + q.z * aw2;
        float al = 1.f / (1.f + __expf(-logit));
        float4 a2v = *(const float4*)&A2[(size_t)s * HID + c4];
        float4 pre;
        pre.x = A1v.x + a2v.x + q.x * w0v.x + q.y * w1v.x + q.z * w2v.x;
        pre.y = A1v.y + a2v.y + q.x * w0v.y + q.y * w1v.y + q.z * w2v.y;
        pre.z = A1v.z + a2v.z + q.x * w0v.z + q.y * w1v.z + q.z * w2v.z;
        pre.w = A1v.w + a2v.w + q.x * w0v.w + q.y * w1v.w + q.z * w2v.w;
        acc.x += al * pre.x; acc.y += al * pre.y;
        acc.z += al * pre.z; acc.w += al * pre.w;
    }
    *(float4*)&part[slot][c4] = acc;
    __syncthreads();
    for (int st = 4; st >= 1; st >>= 1) {
        if (slot < st) {
            float4 p = *(const float4*)&part[slot][c4];
            float4 r = *(const float4*)&part[slot + st][c4];
            p.x += r.x; p.y += r.y; p.z += r.z; p.w += r.w;
            *(float4*)&part[slot][c4] = p;
        }
        __syncthreads();
    }
    if (slot == 0) *(float4*)&hconv[(size_t)n * HID + c4] = *(const float4*)&part[0][c4];
}

// ---------------------------------------------------------------- Fourier-Kolmogorov GEMM (split-f16 MFMA)
// K-split 4 (K=256/block). NO hsh: each trig thread reads its own 16 h floats
// directly from global (same channels serve both frequency groups of the
// K-slice), computes 4 octets, stores padded LDS A-planes. ONE barrier, then a
// barrier-free ds_read + global-B + MFMA stream. LDS 33.8 KB -> 4 blocks/CU.
#define FK_AST  264        // f16 per staged-A row (256 + 8 pad) = 528 B, 16B-aligned
__global__ __launch_bounds__(256) void k_fk(const float* __restrict__ h,
        const _Float16* __restrict__ whi, const _Float16* __restrict__ wlo,
        float* __restrict__ p0, float* __restrict__ p1,
        float* __restrict__ p2, float* __restrict__ p3, int N) {
    __shared__ _Float16 ahi[32 * FK_AST];
    __shared__ _Float16 alo[32 * FK_AST];
    int tid = threadIdx.x;
    int bx = blockIdx.x;
    int nb = (bx >> 2) * 32;
    int ks = bx & 3;
    int kbase = ks * 256;           // covers freq fr0, fr0+1 over channels 0..127
    int fr0 = kbase >> 7;
    {
        int row = tid >> 3;         // 0..31
        int o8 = tid & 7;           // channel octet selector
        int gn = nb + row;
        int rc = (gn < N) ? gn : (N - 1);
        const float* hp = h + (size_t)rc * HID + o8 * 8;
        float hv[2][8];
        *(float4*)&hv[0][0] = *(const float4*)hp;
        *(float4*)&hv[0][4] = *(const float4*)(hp + 4);
        *(float4*)&hv[1][0] = *(const float4*)(hp + 64);
        *(float4*)&hv[1][4] = *(const float4*)(hp + 68);
#pragma unroll
        for (int g = 0; g < 2; ++g) {
            float freqf = 6.2831853f * (float)(fr0 + g + 1);
#pragma unroll
            for (int s = 0; s < 2; ++s) {
                half8 vh, vl;
#pragma unroll
                for (int j = 0; j < 8; ++j) {
                    float ang = freqf * hv[s][j] + 0.78539816f;
                    float a = 1.41421356f * __sinf(ang);   // sin + cos
                    _Float16 hi = (_Float16)a;
                    vh[j] = hi;
                    vl[j] = (_Float16)((a - (float)hi) * 2048.f);
                }
                int oct = g * 16 + s * 8 + o8;   // local k-octet in [0,32)
                *(half8*)&ahi[row * FK_AST + oct * 8] = vh;
                *(half8*)&alo[row * FK_AST + oct * 8] = vl;
            }
        }
    }
    __syncthreads();
    int lane = tid & 63, wv = tid >> 6;
    int quad = lane >> 4, l16 = lane & 15;
    int n0w = wv * 32;
    f4 acc0[2][2], accL[2][2];
#pragma unroll
    for (int mi = 0; mi < 2; ++mi)
#pragma unroll
        for (int ni = 0; ni < 2; ++ni) { acc0[mi][ni] = (f4)(0.f); accL[mi][ni] = (f4)(0.f); }
    const _Float16* bhp0 = whi + (size_t)(n0w + l16) * 1024 + kbase + quad * 8;
    const _Float16* bhp1 = whi + (size_t)(n0w + 16 + l16) * 1024 + kbase + quad * 8;
    const _Float16* blp0 = wlo + (size_t)(n0w + l16) * 1024 + kbase + quad * 8;
    const _Float16* blp1 = wlo + (size_t)(n0w + 16 + l16) * 1024 + kbase + quad * 8;
#pragma unroll 2
    for (int step = 0; step < 8; ++step) {
        int ka = step * 32 + quad * 8;
        half8 ah0 = *(const half8*)&ahi[l16 * FK_AST + ka];
        half8 ah1 = *(const half8*)&ahi[(l16 + 16) * FK_AST + ka];
        half8 al0 = *(const half8*)&alo[l16 * FK_AST + ka];
        half8 al1 = *(const half8*)&alo[(l16 + 16) * FK_AST + ka];
        int ko = step * 32;
        half8 bh0 = *(const half8*)(bhp0 + ko);
        half8 bh1 = *(const half8*)(bhp1 + ko);
        half8 bl0 = *(const half8*)(blp0 + ko);
        half8 bl1 = *(const half8*)(blp1 + ko);
        acc0[0][0] = __builtin_amdgcn_mfma_f32_16x16x32_f16(ah0, bh0, acc0[0][0], 0, 0, 0);
        acc0[0][1] = __builtin_amdgcn_mfma_f32_16x16x32_f16(ah0, bh1, acc0[0][1], 0, 0, 0);
        acc0[1][0] = __builtin_amdgcn_mfma_f32_16x16x32_f16(ah1, bh0, acc0[1][0], 0, 0, 0);
        acc0[1][1] = __builtin_amdgcn_mfma_f32_16x16x32_f16(ah1, bh1, acc0[1][1], 0, 0, 0);
        accL[0][0] = __builtin_amdgcn_mfma_f32_16x16x32_f16(ah0, bl0, accL[0][0], 0, 0, 0);
        accL[0][1] = __builtin_amdgcn_mfma_f32_16x16x32_f16(ah0, bl1, accL[0][1], 0, 0, 0);
        accL[1][0] = __builtin_amdgcn_mfma_f32_16x16x32_f16(ah1, bl0, accL[1][0], 0, 0, 0);
        accL[1][1] = __builtin_amdgcn_mfma_f32_16x16x32_f16(ah1, bl1, accL[1][1], 0, 0, 0);
        accL[0][0] = __builtin_amdgcn_mfma_f32_16x16x32_f16(al0, bh0, accL[0][0], 0, 0, 0);
        accL[0][1] = __builtin_amdgcn_mfma_f32_16x16x32_f16(al0, bh1, accL[0][1], 0, 0, 0);
        accL[1][0] = __builtin_amdgcn_mfma_f32_16x16x32_f16(al1, bh0, accL[1][0], 0, 0, 0);
        accL[1][1] = __builtin_amdgcn_mfma_f32_16x16x32_f16(al1, bh1, accL[1][1], 0, 0, 0);
    }
    float* p = (ks == 0) ? p0 : (ks == 1) ? p1 : (ks == 2) ? p2 : p3;
    const float inv = 1.0f / 2048.0f;
#pragma unroll
    for (int mi = 0; mi < 2; ++mi)
#pragma unroll
        for (int ni = 0; ni < 2; ++ni)
#pragma unroll
            for (int r = 0; r < 4; ++r) {
                int gn = nb + mi * 16 + quad * 4 + r;
                if (gn < N)
                    p[gn * HID + n0w + ni * 16 + l16] = acc0[mi][ni][r] + accL[mi][ni][r] * inv;
            }
}

// ---------------------------------------------------------------- batchnorm stats (5 streams)
__global__ void k_bn_stats(float* __restrict__ hconv,
                           const float* __restrict__ p0, const float* __restrict__ p1,
                           const float* __restrict__ p2, const float* __restrict__ p3,
                           const float* __restrict__ fkb,
                           double* __restrict__ stats, int N) {
    int c = threadIdx.x & 127, half = threadIdx.x >> 7;
    float bias = fkb[c];
    float s = 0.f, s2 = 0.f;
    for (int n = blockIdx.x * 2 + half; n < N; n += gridDim.x * 2) {
        int idx = n * HID + c;
        float v = hconv[idx] + p0[idx] + p1[idx] + p2[idx] + p3[idx] + bias;
        hconv[idx] = v;
        s += v; s2 += v * v;
    }
    __shared__ float sh[256], sh2[256];
    sh[threadIdx.x] = s; sh2[threadIdx.x] = s2;
    __syncthreads();
    if (half == 0) {
        s = sh[c] + sh[128 + c];
        s2 = sh2[c] + sh2[128 + c];
        atomicAdd(&stats[c], (double)s);
        atomicAdd(&stats[128 + c], (double)s2);
    }
}

// bn_final folded in; optionally computes pool scores (last layer)
__global__ void k_bn_apply(const float* __restrict__ hsum, const double* __restrict__ stats,
                           const float* __restrict__ g, const float* __restrict__ b,
                           const float* __restrict__ pw, const float* __restrict__ pb,
                           float* __restrict__ h, float* __restrict__ s,
                           int do_score, int N) {
    __shared__ float red[4];
    int idx = blockIdx.x * 256 + threadIdx.x;
    int valid = idx < N * HID;
    int c = idx & 127;
    double invN = 1.0 / (double)N;
    float mu = (float)(stats[c] * invN);
    float var = (float)(stats[128 + c] * invN) - mu * mu;
    float inv = 1.f / sqrtf(var + 1e-5f);
    float sc = g[c] * inv;
    float sh = b[c] - mu * sc;
    float o = 0.f;
    if (valid) {
        o = fmaxf(hsum[idx] * sc + sh, 0.f);
        h[idx] = o;
    }
    if (do_score) {
        float p = valid ? o * pw[c] : 0.f;
        for (int off = 32; off > 0; off >>= 1) p += __shfl_down(p, off);
        int wid = threadIdx.x >> 6;
        if ((threadIdx.x & 63) == 0) red[wid] = p;
        __syncthreads();
        int row = idx >> 7;
        int half = threadIdx.x >> 7;
        if ((threadIdx.x & 127) == 0 && row < N)
            s[row] = red[half * 2] + red[half * 2 + 1] + pb[0];
    }
}

// ---------------------------------------------------------------- softmax partials
__global__ void k_smax1(const float* __restrict__ s, float* __restrict__ mzp, int N) {
    __shared__ float red[256];
    float m = -INFINITY;
    for (int n = blockIdx.x * 256 + threadIdx.x; n < N; n += SMAXB * 256)
        m = fmaxf(m, s[n]);
    red[threadIdx.x] = m;
    __syncthreads();
    for (int off = 128; off > 0; off >>= 1) {
        if (threadIdx.x < (unsigned)off)
            red[threadIdx.x] = fmaxf(red[threadIdx.x], red[threadIdx.x + off]);
        __syncthreads();
    }
    m = red[0];
    __syncthreads();
    float z = 0.f;
    for (int n = blockIdx.x * 256 + threadIdx.x; n < N; n += SMAXB * 256)
        z += __expf(s[n] - m);
    red[threadIdx.x] = z;
    __syncthreads();
    for (int off = 128; off > 0; off >>= 1) {
        if (threadIdx.x < (unsigned)off) red[threadIdx.x] += red[threadIdx.x + off];
        __syncthreads();
    }
    if (threadIdx.x == 0) { mzp[blockIdx.x * 2] = m; mzp[blockIdx.x * 2 + 1] = red[0]; }
}

__device__ __forceinline__ void combine_mz(const float* mzp, float& m, float& Z) {
    m = -INFINITY;
#pragma unroll 8
    for (int i = 0; i < SMAXB; ++i) m = fmaxf(m, mzp[i * 2]);
    Z = 0.f;
#pragma unroll 8
    for (int i = 0; i < SMAXB; ++i) Z += mzp[i * 2 + 1] * __expf(mzp[i * 2] - m);
}

// ---------------------------------------------------------------- attention pool (split)
__global__ void k_pool_part(const float* __restrict__ h, const float* __restrict__ s,
                            const float* __restrict__ mzp, const int* __restrict__ boffs,
                            float* __restrict__ part) {
    int b = blockIdx.x >> 4, split = blockIdx.x & (PSPLIT - 1);
    int c = threadIdx.x & 127, half = threadIdx.x >> 7;
    float m, Z;
    combine_mz(mzp, m, Z);
    (void)Z;
    int n0 = boffs[b], n1 = boffs[b + 1];
    float acc = 0.f;
    for (int n = n0 + split * 2 + half; n < n1; n += PSPLIT * 2)
        acc += __expf(s[n] - m) * h[n * HID + c];
    __shared__ float prt[2][HID];
    prt[half][c] = acc;
    __syncthreads();
    if (half == 0) part[(size_t)(b * PSPLIT + split) * HID + c] = prt[0][c] + prt[1][c];
}

__global__ void k_pool_sum(const float* __restrict__ part, const float* __restrict__ mzp,
                           float* __restrict__ pooled) {
    int b = blockIdx.x, c = threadIdx.x;
    float m, Z;
    combine_mz(mzp, m, Z);
    float acc = 0.f;
#pragma unroll
    for (int i = 0; i < PSPLIT; ++i) acc += part[(size_t)(b * PSPLIT + i) * HID + c];
    pooled[b * HID + c] = acc / Z;
}

// ---------------------------------------------------------------- heads (grid = B*4)
__global__ __launch_bounds__(256) void k_head(const float* __restrict__ pooled,
                       const float* __restrict__ sg_table,
                       const int* __restrict__ space_group,
                       const float* __restrict__ hw1, const float* __restrict__ hb1,
                       const float* __restrict__ ew2, const float* __restrict__ eb2,
                       const float* __restrict__ sw2, const float* __restrict__ sb2,
                       const float* __restrict__ cw2, const float* __restrict__ cb2,
                       const float* __restrict__ mw2, const float* __restrict__ mb2,
                       float* __restrict__ out, int B) {
    __shared__ float comb[256];
    __shared__ float zred[2][128];
    __shared__ float zsh[128];
    int b = blockIdx.x >> 2, i = blockIdx.x & 3;
    int t = threadIdx.x;
    comb[t] = (t < 128) ? pooled[b * HID + t] : sg_table[space_group[b] * HID + (t - 128)];
    __syncthreads();
    int half = t >> 7, tt = t & 127;
    const float* W = hw1 + ((size_t)i * 256 + half * 128) * HID;
    const float* cb = &comb[half * 128];
    float z = 0.f;
#pragma unroll 8
    for (int k = 0; k < 128; ++k) z += cb[k] * W[k * HID + tt];
    zred[half][tt] = z;
    __syncthreads();
    if (t < 128) zsh[t] = fmaxf(zred[0][t] + zred[1][t] + hb1[i * HID + t], 0.f);
    __syncthreads();
    const int od[4] = {1, 3, 7, 3};
    const int base[4] = {0, 64, 256, 704};
    const float* w2 = (i == 0) ? ew2 : (i == 1) ? sw2 : (i == 2) ? cw2 : mw2;
    const float* b2 = (i == 0) ? eb2 : (i == 1) ? sb2 : (i == 2) ? cb2 : mb2;
    int odi = od[i];
    if (t < odi) {
        float o = b2[t];
        for (int c = 0; c < HID; ++c) o += zsh[c] * w2[c * odi + t];
        out[base[i] + b * odi + t] = o;
    }
}

// ---------------------------------------------------------------- launch
extern "C" void kernel_launch(void* const* d_in, const int* in_sizes, int n_in,
                              void* d_out, int out_size, void* d_ws, size_t ws_size,
                              hipStream_t stream) {
    const float* x          = (const float*)d_in[0];
    const int*   edge_index = (const int*)d_in[1];
    const float* edge_attr  = (const float*)d_in[2];
    const int*   batch      = (const int*)d_in[3];
    const int*   space_group= (const int*)d_in[4];
    const float* node_w     = (const float*)d_in[5];
    const float* node_b     = (const float*)d_in[6];
    const float* sg_table   = (const float*)d_in[7];
    const float* lin_w      = (const float*)d_in[8];
    const float* lin_b      = (const float*)d_in[9];
    const float* att_w      = (const float*)d_in[10];
    const float* att_b      = (const float*)d_in[11];
    const float* fk_w       = (const float*)d_in[12];
    const float* fk_b       = (const float*)d_in[13];
    const float* bn_g       = (const float*)d_in[14];
    const float* bn_b       = (const float*)d_in[15];
    const float* pool_w     = (const float*)d_in[16];
    const float* pool_b     = (const float*)d_in[17];
    const float* head_w1    = (const float*)d_in[18];
    const float* head_b1    = (const float*)d_in[19];
    const float* ew2 = (const float*)d_in[20]; const float* eb2 = (const float*)d_in[21];
    const float* sw2 = (const float*)d_in[22]; const float* sb2 = (const float*)d_in[23];
    const float* cw2 = (const float*)d_in[24]; const float* cb2 = (const float*)d_in[25];
    const float* mw2 = (const float*)d_in[26]; const float* mb2 = (const float*)d_in[27];
    float* out = (float*)d_out;

    const int N = in_sizes[3];
    const int E = in_sizes[1] / 2;
    const int B = in_sizes[4];
    const int* src = edge_index;
    const int* dst = edge_index + E;

    char* w = (char*)d_ws;
    auto alloc = [&](size_t bytes) { char* p = w; w += (bytes + 255) & ~(size_t)255; return p; };
    float*  h      = (float*)alloc((size_t)N * HID * 4);
    float*  A1     = (float*)alloc((size_t)N * HID * 4);  // reused as FK partial 0
    float*  A2     = (float*)alloc((size_t)N * HID * 4);  // reused as FK partial 1
    float*  p2     = (float*)alloc((size_t)N * HID * 4);  // FK partial 2
    float*  p3     = (float*)alloc((size_t)N * HID * 4);  // FK partial 3
    float*  hconv  = (float*)alloc((size_t)N * HID * 4);  // becomes pre-BN sum in place
    float*  a1     = (float*)alloc((size_t)N * 4);
    float*  a2     = (float*)alloc((size_t)N * 4);
    float*  sbuf   = (float*)alloc((size_t)N * 4);
    int*    deg    = (int*)alloc((size_t)N * 4);
    int*    cursor = (int*)alloc((size_t)N * 4);
    int*    offs   = (int*)alloc((size_t)(N + 1) * 4);
    int*    eord   = (int*)alloc((size_t)E * 4);
    int*    srco   = (int*)alloc((size_t)E * 4);
    float4* ea3o   = (float4*)alloc((size_t)E * 16);
    _Float16* whi  = (_Float16*)alloc((size_t)DEPTH * 1024 * HID * 2);
    _Float16* wlo  = (_Float16*)alloc((size_t)DEPTH * 1024 * HID * 2);
    int*    bsum   = (int*)alloc(256 * 4);
    int*    boffs  = (int*)alloc((size_t)(B + 1) * 4);
    double* stats  = (double*)alloc(256 * 8);
    float*  mzp    = (float*)alloc(SMAXB * 2 * 4);
    float*  part   = (float*)alloc((size_t)B * PSPLIT * HID * 4);
    float*  pooled = (float*)alloc((size_t)B * HID * 4);

    const int nchunk = (N + 255) / 256;
    const int echunk = (E + 255) / 256;

    // one-time per launch: W split + CSR build
    k_wsplit<<<128, 256, 0, stream>>>(fk_w, whi, wlo);
    hipMemsetAsync(deg, 0, (size_t)N * 4, stream);
    k_hist<<<echunk, 256, 0, stream>>>(dst, deg, E);
    k_scan_a<<<nchunk, 256, 0, stream>>>(deg, bsum, N);
    k_scan_b<<<1, 256, 0, stream>>>(bsum, nchunk);
    k_scan_c<<<nchunk, 256, 0, stream>>>(deg, bsum, offs, cursor, N);
    k_scatter<<<echunk, 256, 0, stream>>>(src, dst, cursor, eord, srco, E);
    k_eaord<<<echunk, 256, 0, stream>>>(eord, edge_attr, ea3o, E);
    k_bstart<<<nchunk, 256, 0, stream>>>(batch, boffs, N, B);

    k_node_embed<<<(N * HID + 255) / 256, 256, 0, stream>>>(x, node_w, node_b, h, N);

    for (int l = 0; l < DEPTH; ++l) {
        const float* linw_l = lin_w + (size_t)l * 259 * HID;
        k_node_lin<<<(N + 7) / 8, 256, 0, stream>>>(
            h, linw_l, lin_b + l * HID, att_w + (size_t)l * 259, att_b + l,
            A1, A2, a1, a2, N);
        k_edge<<<N, 256, 0, stream>>>(A1, A2, a1, a2, srco, ea3o, offs,
                                      linw_l + 256 * HID, att_w + (size_t)l * 259 + 256,
                                      hconv, stats, N);
        k_fk<<<((N + 31) / 32) * 4, 256, 0, stream>>>(
            h, whi + (size_t)l * 131072, wlo + (size_t)l * 131072, A1, A2, p2, p3, N);
        k_bn_stats<<<320, 256, 0, stream>>>(hconv, A1, A2, p2, p3, fk_b + l * HID, stats, N);
        k_bn_apply<<<(N * HID + 255) / 256, 256, 0, stream>>>(
            hconv, stats, bn_g + l * HID, bn_b + l * HID, pool_w, pool_b,
            h, sbuf, (l == DEPTH - 1) ? 1 : 0, N);
    }

    k_smax1<<<SMAXB, 256, 0, stream>>>(sbuf, mzp, N);
    k_pool_part<<<B * PSPLIT, 256, 0, stream>>>(h, sbuf, mzp, boffs, part);
    k_pool_sum<<<B, 128, 0, stream>>>(part, mzp, pooled);
    k_head<<<B * 4, 256, 0, stream>>>(pooled, sg_table, space_group, head_w1, head_b1,
                                      ew2, eb2, sw2, sb2, cw2, cb2, mw2, mb2, out, B);
}